// Round 1
// baseline (10262.833 us; speedup 1.0000x reference)
//
#include <hip/hip_runtime.h>
#include <hip/hip_bf16.h>

// ---------------------------------------------------------------------------
// Sizes (compile-time constants from the reference)
// HID=512 POOL=4096 N_OBJ_CLS=151 N_REL_CLS=51 EMB=200 N_OBJ=1024 N_REL=128
// ---------------------------------------------------------------------------

// ======================= generic f32 GEMM (64x64 tile) ======================
// C[M,N] = A[M,K] @ B + bias (+ optional elementwise mul, relu)
// BT=false: B is (K,N) row-major.  BT=true: B is (N,K) row-major (B^T).
// Requires M%64==0, N%64==0, K%16==0.
template<bool BT, bool RELU, bool MUL>
__global__ __launch_bounds__(256) void gemm_kernel(
    const float* __restrict__ A, const float* __restrict__ B,
    const float* __restrict__ bias, const float* __restrict__ mulp,
    float* __restrict__ C, int M, int N, int K)
{
    __shared__ float As[16][68];
    __shared__ float Bs[16][68];
    const int m0 = blockIdx.x * 64, n0 = blockIdx.y * 64;
    const int tid = threadIdx.x;
    const int ty = tid >> 4, tx = tid & 15;
    float acc[4][4] = {};
    for (int k0 = 0; k0 < K; k0 += 16) {
        {   // A tile: 64 rows x 16 k
            const int m = tid >> 2, kq = (tid & 3) << 2;
            const float4 a = *reinterpret_cast<const float4*>(A + (size_t)(m0 + m) * K + k0 + kq);
            As[kq + 0][m] = a.x; As[kq + 1][m] = a.y; As[kq + 2][m] = a.z; As[kq + 3][m] = a.w;
        }
        if (!BT) {
            const int kk = tid >> 4, nq = (tid & 15) << 2;
            const float4 b = *reinterpret_cast<const float4*>(B + (size_t)(k0 + kk) * N + n0 + nq);
            *reinterpret_cast<float4*>(&Bs[kk][nq]) = b;
        } else {
            const int nn = tid >> 2, kq = (tid & 3) << 2;
            const float4 b = *reinterpret_cast<const float4*>(B + (size_t)(n0 + nn) * K + k0 + kq);
            Bs[kq + 0][nn] = b.x; Bs[kq + 1][nn] = b.y; Bs[kq + 2][nn] = b.z; Bs[kq + 3][nn] = b.w;
        }
        __syncthreads();
#pragma unroll
        for (int k = 0; k < 16; ++k) {
            const float4 av = *reinterpret_cast<const float4*>(&As[k][ty << 2]);
            const float4 bv = *reinterpret_cast<const float4*>(&Bs[k][tx << 2]);
            acc[0][0] += av.x * bv.x; acc[0][1] += av.x * bv.y; acc[0][2] += av.x * bv.z; acc[0][3] += av.x * bv.w;
            acc[1][0] += av.y * bv.x; acc[1][1] += av.y * bv.y; acc[1][2] += av.y * bv.z; acc[1][3] += av.y * bv.w;
            acc[2][0] += av.z * bv.x; acc[2][1] += av.z * bv.y; acc[2][2] += av.z * bv.z; acc[2][3] += av.z * bv.w;
            acc[3][0] += av.w * bv.x; acc[3][1] += av.w * bv.y; acc[3][2] += av.w * bv.z; acc[3][3] += av.w * bv.w;
        }
        __syncthreads();
    }
#pragma unroll
    for (int i = 0; i < 4; ++i) {
        const int m = m0 + (ty << 2) + i;
#pragma unroll
        for (int j = 0; j < 4; ++j) {
            const int n = n0 + (tx << 2) + j;
            float v = acc[i][j] + bias[n];
            if (MUL) v *= mulp[(size_t)m * N + n];
            if (RELU) v = fmaxf(v, 0.f);
            C[(size_t)m * N + n] = v;
        }
    }
}

// ======================= conv1: 5x5, CI=1, fused outer-product input, relu+pool2
// input x[n,i,j] = emb[p0[n]+1, i] * emb[p1[n]+1, j]  (200x200, pad 2)
// output: (chunk, 64, 100, 100) pooled
__global__ __launch_bounds__(256) void conv1_kernel(
    const float* __restrict__ emb, const int* __restrict__ pair,
    const float* __restrict__ wgt, const float* __restrict__ bias,
    float* __restrict__ out, int n0)
{
    const int n = blockIdx.x;
    const int gn = n0 + n;
    constexpr int CO_T = 16;
    const int co0 = blockIdx.y * CO_T;
    const int p = blockIdx.z * 256 + threadIdx.x;
    if (p >= 100 * 100) return;
    const int py = p / 100, px = p - py * 100;
    const int i0 = 2 * py - 2, j0 = 2 * px - 2;
    const float* oe = emb + (size_t)(pair[2 * gn + 0] + 1) * 200;
    const float* se = emb + (size_t)(pair[2 * gn + 1] + 1) * 200;
    float ov[6], sv[6];
#pragma unroll
    for (int t = 0; t < 6; ++t) {
        const int i = i0 + t, j = j0 + t;
        ov[t] = ((unsigned)i < 200u) ? oe[i] : 0.f;
        sv[t] = ((unsigned)j < 200u) ? se[j] : 0.f;
    }
    float xm[6][6];
#pragma unroll
    for (int r = 0; r < 6; ++r)
#pragma unroll
        for (int c = 0; c < 6; ++c) xm[r][c] = ov[r] * sv[c];
#pragma unroll 1
    for (int c = 0; c < CO_T; ++c) {
        const float* wc = wgt + (size_t)(co0 + c) * 25;
        float s0, s1, s2, s3;
        s0 = s1 = s2 = s3 = bias[co0 + c];
#pragma unroll
        for (int dy = 0; dy < 5; ++dy)
#pragma unroll
            for (int dx = 0; dx < 5; ++dx) {
                const float wv = wc[dy * 5 + dx];
                s0 += xm[dy][dx] * wv;
                s1 += xm[dy][dx + 1] * wv;
                s2 += xm[dy + 1][dx] * wv;
                s3 += xm[dy + 1][dx + 1] * wv;
            }
        const float v = 0.25f * (fmaxf(s0, 0.f) + fmaxf(s1, 0.f) + fmaxf(s2, 0.f) + fmaxf(s3, 0.f));
        out[(((size_t)n * 64 + co0 + c) * 100 + py) * 100 + px] = v;
    }
}

// ======================= generic 3x3 conv, pad1, relu, optional fused 2x2 meanpool
template<int CI, int HW, int CO_T, bool POOL>
__global__ __launch_bounds__(256) void conv3x3_kernel(
    const float* __restrict__ in, const float* __restrict__ wgt,
    const float* __restrict__ bias, float* __restrict__ out, int CO)
{
    constexpr int H = HW, W = HW;
    constexpr int OH = POOL ? H / 2 : H;
    constexpr int OW = POOL ? W / 2 : W;
    constexpr int NPIX = OH * OW;
    const int n = blockIdx.x;
    const int co0 = blockIdx.y * CO_T;
    const int p = blockIdx.z * 256 + threadIdx.x;
    if (p >= NPIX) return;
    const int py = p / OW, px = p - py * OW;
    constexpr int NP = POOL ? 4 : 1;
    constexpr int WIN = POOL ? 4 : 3;
    float acc[CO_T][NP];
#pragma unroll
    for (int c = 0; c < CO_T; ++c) {
        const float b = bias[co0 + c];
#pragma unroll
        for (int q = 0; q < NP; ++q) acc[c][q] = b;
    }
    const int iy0 = (POOL ? 2 * py : py) - 1;
    const int ix0 = (POOL ? 2 * px : px) - 1;
    const float* inbase = in + (size_t)n * CI * H * W;
#pragma unroll 1
    for (int ci = 0; ci < CI; ++ci) {
        const float* ip = inbase + (size_t)ci * H * W;
        float win[WIN][WIN];
#pragma unroll
        for (int r = 0; r < WIN; ++r) {
            const int iy = iy0 + r;
            const bool vy = (unsigned)iy < (unsigned)H;
#pragma unroll
            for (int c2 = 0; c2 < WIN; ++c2) {
                const int ix = ix0 + c2;
                win[r][c2] = (vy && (unsigned)ix < (unsigned)W) ? ip[iy * W + ix] : 0.f;
            }
        }
        const float* wp = wgt + ((size_t)co0 * CI + ci) * 9;
#pragma unroll
        for (int c = 0; c < CO_T; ++c) {
            const float* wc = wp + (size_t)c * CI * 9;
            const float w0 = wc[0], w1 = wc[1], w2 = wc[2], w3 = wc[3], w4 = wc[4],
                        w5 = wc[5], w6 = wc[6], w7 = wc[7], w8 = wc[8];
#pragma unroll
            for (int q = 0; q < NP; ++q) {
                const int sy = POOL ? (q >> 1) : 0;
                const int sx = POOL ? (q & 1) : 0;
                acc[c][q] += win[sy][sx] * w0 + win[sy][sx + 1] * w1 + win[sy][sx + 2] * w2
                           + win[sy + 1][sx] * w3 + win[sy + 1][sx + 1] * w4 + win[sy + 1][sx + 2] * w5
                           + win[sy + 2][sx] * w6 + win[sy + 2][sx + 1] * w7 + win[sy + 2][sx + 2] * w8;
            }
        }
    }
#pragma unroll
    for (int c = 0; c < CO_T; ++c) {
        float v;
        if (POOL)
            v = 0.25f * (fmaxf(acc[c][0], 0.f) + fmaxf(acc[c][1], 0.f) +
                         fmaxf(acc[c][2], 0.f) + fmaxf(acc[c][3], 0.f));
        else
            v = fmaxf(acc[c][0], 0.f);
        out[(((size_t)n * CO + co0 + c) * OH + py) * OW + px] = v;
    }
}

// spatial mean over S elements: in (chunk, CO, S) -> gap[(n0+n), co]
__global__ __launch_bounds__(64) void mean_kernel(
    const float* __restrict__ in, float* __restrict__ gap, int n0, int CO, int S)
{
    const int n = blockIdx.x, co = blockIdx.y;
    const float* ip = in + ((size_t)n * CO + co) * S;
    float s = 0.f;
    for (int i = threadIdx.x; i < S; i += 64) s += ip[i];
#pragma unroll
    for (int off = 32; off > 0; off >>= 1) s += __shfl_down(s, off, 64);
    if (threadIdx.x == 0) gap[((size_t)(n0 + n)) * CO + co] = s / (float)S;
}

// prod_rep[r,0:512]=edge_rep[p0[r],0:512]; prod_rep[r,512:1024]=edge_rep[p1[r],512:1024]
__global__ __launch_bounds__(256) void prod_kernel(
    const float* __restrict__ er, const int* __restrict__ pair, float* __restrict__ pr)
{
    const int r = blockIdx.x;
    const int p0 = pair[2 * r], p1 = pair[2 * r + 1];
    for (int i = threadIdx.x; i < 1024; i += 256) {
        const int src = (i < 512) ? p0 : p1;
        pr[(size_t)r * 1024 + i] = er[(size_t)src * 1024 + i];
    }
}

// rcat[r] = [prod[r,0:512], edge_feats[r,0:512], prod[r,512:1024]]
__global__ __launch_bounds__(256) void rcat_kernel(
    const float* __restrict__ prodr, const float* __restrict__ ef, float* __restrict__ rc)
{
    const int r = blockIdx.x;
    for (int i = threadIdx.x; i < 1536; i += 256) {
        float v;
        if (i < 512)       v = prodr[(size_t)r * 1024 + i];
        else if (i < 1024) v = ef[(size_t)r * 512 + (i - 512)];
        else               v = prodr[(size_t)r * 1024 + (i - 1024) + 512];
        rc[(size_t)r * 1536 + i] = v;
    }
}

// cat8[r] = [pwe[r,0:4096], union[r,0:4096]]
__global__ __launch_bounds__(256) void cat8_kernel(
    const float* __restrict__ pwe, const float* __restrict__ un, float* __restrict__ cat)
{
    const int r = blockIdx.x;
    for (int i = threadIdx.x; i < 8192; i += 256) {
        cat[(size_t)r * 8192 + i] = (i < 4096) ? pwe[(size_t)r * 4096 + i]
                                               : un[(size_t)r * 4096 + (i - 4096)];
    }
}

// rel_dists = rel_feats @ W_rel + b_rel + freq[c0*151+c1]  -> out[0:128*51]
__global__ __launch_bounds__(256) void reldist_kernel(
    const float* __restrict__ rf, const float* __restrict__ Wr, const float* __restrict__ br,
    const float* __restrict__ freq, const int* __restrict__ preds,
    const int* __restrict__ pair, float* __restrict__ out)
{
    const int idx = blockIdx.x * 256 + threadIdx.x;
    if (idx >= 128 * 51) return;
    const int r = idx / 51, j = idx - r * 51;
    const float* a = rf + (size_t)r * 512;
    float s = br[j];
    for (int k = 0; k < 512; ++k) s += a[k] * Wr[(size_t)k * 51 + j];
    const int c0 = preds[pair[2 * r]], c1 = preds[pair[2 * r + 1]];
    s += freq[((size_t)c0 * 151 + c1) * 51 + j];
    out[idx] = s;
}

// ===========================================================================
extern "C" void kernel_launch(void* const* d_in, const int* in_sizes, int n_in,
                              void* d_out, int out_size, void* d_ws, size_t ws_size,
                              hipStream_t stream)
{
    const float* obj_feats  = (const float*)d_in[0];
    const int*   obj_preds  = (const int*)  d_in[1];
    const int*   pair       = (const int*)  d_in[2];
    const float* unionf     = (const float*)d_in[3];
    const float* W_post_emb = (const float*)d_in[4];
    const float* b_post_emb = (const float*)d_in[5];
    const float* W_post_cat = (const float*)d_in[6];
    const float* b_post_cat = (const float*)d_in[7];
    const float* W_edge     = (const float*)d_in[8];
    const float* b_edge     = (const float*)d_in[9];
    const float* W_lin      = (const float*)d_in[10];
    const float* b_lin      = (const float*)d_in[11];
    const float* W_rel      = (const float*)d_in[12];
    const float* b_rel      = (const float*)d_in[13];
    const float* freq       = (const float*)d_in[14];
    const float* emb        = (const float*)d_in[15];
    const float* cw1 = (const float*)d_in[16]; const float* cb1 = (const float*)d_in[17];
    const float* cw2 = (const float*)d_in[18]; const float* cb2 = (const float*)d_in[19];
    const float* cw3 = (const float*)d_in[20]; const float* cb3 = (const float*)d_in[21];
    const float* cw4 = (const float*)d_in[22]; const float* cb4 = (const float*)d_in[23];
    const float* cw5 = (const float*)d_in[24]; const float* cb5 = (const float*)d_in[25];
    const float* cw6 = (const float*)d_in[26]; const float* cb6 = (const float*)d_in[27];
    const float* Ww1 = (const float*)d_in[28]; const float* bw1 = (const float*)d_in[29];
    const float* Ww2 = (const float*)d_in[30]; const float* bw2 = (const float*)d_in[31];
    float* out = (float*)d_out;

    // ---- workspace layout (floats) ----
    float* ws = (float*)d_ws;
    float* edge_rep   = ws;                       // 1024*1024
    float* prodr      = edge_rep + 1048576;       // 128*1024
    float* visual     = prodr + 131072;           // 128*4096
    float* edge_feats = visual + 524288;          // 128*512
    float* rcat       = edge_feats + 65536;       // 128*1536
    float* rel_feats  = rcat + 196608;            // 128*512
    float* gap        = rel_feats + 65536;        // 128*512
    float* x5         = gap + 65536;              // 128*384
    float* pwe        = x5 + 49152;               // 128*4096
    float* cat8       = pwe + 524288;             // 128*8192
    float* hbuf       = cat8 + 1048576;           // 128*512
    const size_t persist = 3784704ull;            // floats

    // chunk the conv pipeline through ws (5.76 MB/sample for p1..c4)
    int C = 128;
    while (C > 1 && (persist + (size_t)C * 1440000ull) * 4ull > ws_size) C >>= 1;
    float* p1 = hbuf + 65536;                 // C*64*100*100
    float* p2 = p1 + (size_t)C * 640000;      // C*128*50*50
    float* p3 = p2 + (size_t)C * 320000;      // C*256*25*25
    float* c4 = p3 + (size_t)C * 160000;      // C*512*25*25

    // ---- relation branch ----
    gemm_kernel<false,false,false><<<dim3(16,16),256,0,stream>>>(obj_feats, W_post_emb, b_post_emb, nullptr, edge_rep, 1024,1024,512);
    prod_kernel<<<dim3(128),256,0,stream>>>(edge_rep, pair, prodr);
    gemm_kernel<false,false,true ><<<dim3(2,64),256,0,stream>>>(prodr, W_post_cat, b_post_cat, unionf, visual, 128,4096,1024);
    gemm_kernel<false,true ,false><<<dim3(2,8),256,0,stream>>>(visual, W_edge, b_edge, nullptr, edge_feats, 128,512,4096);
    rcat_kernel<<<dim3(128),256,0,stream>>>(prodr, edge_feats, rcat);
    gemm_kernel<false,false,false><<<dim3(2,8),256,0,stream>>>(rcat, W_lin, b_lin, nullptr, rel_feats, 128,512,1536);
    reldist_kernel<<<dim3(26),256,0,stream>>>(rel_feats, W_rel, b_rel, freq, obj_preds, pair, out);

    // ---- conv chain (chunked over batch) ----
    for (int n0 = 0; n0 < 128; n0 += C) {
        conv1_kernel<<<dim3(C,4,40),256,0,stream>>>(emb, pair, cw1, cb1, p1, n0);
        conv3x3_kernel<64,100,16,true ><<<dim3(C,8,10),256,0,stream>>>(p1, cw2, cb2, p2, 128);
        conv3x3_kernel<128,50,16,true ><<<dim3(C,16,3),256,0,stream>>>(p2, cw3, cb3, p3, 256);
        conv3x3_kernel<256,25,32,false><<<dim3(C,16,3),256,0,stream>>>(p3, cw4, cb4, c4, 512);
        mean_kernel<<<dim3(C,512),64,0,stream>>>(c4, gap, n0, 512, 625);
    }

    // ---- conv tail (1x1 convs as GEMMs, B^T layout) ----
    gemm_kernel<true ,true ,false><<<dim3(2,6),256,0,stream>>>(gap, cw5, cb5, nullptr, x5, 128,384,512);
    gemm_kernel<true ,false,false><<<dim3(2,64),256,0,stream>>>(x5, cw6, cb6, nullptr, pwe, 128,4096,384);

    // ---- union head ----
    cat8_kernel<<<dim3(128),256,0,stream>>>(pwe, unionf, cat8);
    gemm_kernel<false,true ,false><<<dim3(2,8),256,0,stream>>>(cat8, Ww1, bw1, nullptr, hbuf, 128,512,8192);
    gemm_kernel<false,true ,false><<<dim3(2,64),256,0,stream>>>(hbuf, Ww2, bw2, nullptr, out + 6528, 128,4096,512);
}

// Round 2
// 5395.702 us; speedup vs baseline: 1.9020x; 1.9020x over previous
//
#include <hip/hip_runtime.h>
#include <hip/hip_bf16.h>

// ---------------------------------------------------------------------------
// HID=512 POOL=4096 N_OBJ_CLS=151 N_REL_CLS=51 EMB=200 N_OBJ=1024 N_REL=128
// ---------------------------------------------------------------------------

typedef __attribute__((ext_vector_type(8))) short  s16x8;
typedef __attribute__((ext_vector_type(4))) short  s16x4;
typedef __attribute__((ext_vector_type(4))) float  f32x4;

__device__ inline unsigned short f2bf(float f) {
    unsigned u = __builtin_bit_cast(unsigned, f);
    u = (u + 0x7FFF + ((u >> 16) & 1)) >> 16;
    return (unsigned short)u;
}
__device__ inline float bf2f(unsigned short s) {
    unsigned u = ((unsigned)s) << 16;
    return __builtin_bit_cast(float, u);
}

// ======================= generic f32 GEMM (64x64 tile) ======================
template<bool BT, bool RELU, bool MUL>
__global__ __launch_bounds__(256) void gemm_kernel(
    const float* __restrict__ A, const float* __restrict__ B,
    const float* __restrict__ bias, const float* __restrict__ mulp,
    float* __restrict__ C, int M, int N, int K)
{
    __shared__ float As[16][68];
    __shared__ float Bs[16][68];
    const int m0 = blockIdx.x * 64, n0 = blockIdx.y * 64;
    const int tid = threadIdx.x;
    const int ty = tid >> 4, tx = tid & 15;
    float acc[4][4] = {};
    for (int k0 = 0; k0 < K; k0 += 16) {
        {
            const int m = tid >> 2, kq = (tid & 3) << 2;
            const float4 a = *reinterpret_cast<const float4*>(A + (size_t)(m0 + m) * K + k0 + kq);
            As[kq + 0][m] = a.x; As[kq + 1][m] = a.y; As[kq + 2][m] = a.z; As[kq + 3][m] = a.w;
        }
        if (!BT) {
            const int kk = tid >> 4, nq = (tid & 15) << 2;
            const float4 b = *reinterpret_cast<const float4*>(B + (size_t)(k0 + kk) * N + n0 + nq);
            *reinterpret_cast<float4*>(&Bs[kk][nq]) = b;
        } else {
            const int nn = tid >> 2, kq = (tid & 3) << 2;
            const float4 b = *reinterpret_cast<const float4*>(B + (size_t)(n0 + nn) * K + k0 + kq);
            Bs[kq + 0][nn] = b.x; Bs[kq + 1][nn] = b.y; Bs[kq + 2][nn] = b.z; Bs[kq + 3][nn] = b.w;
        }
        __syncthreads();
#pragma unroll
        for (int k = 0; k < 16; ++k) {
            const float4 av = *reinterpret_cast<const float4*>(&As[k][ty << 2]);
            const float4 bv = *reinterpret_cast<const float4*>(&Bs[k][tx << 2]);
            acc[0][0] += av.x * bv.x; acc[0][1] += av.x * bv.y; acc[0][2] += av.x * bv.z; acc[0][3] += av.x * bv.w;
            acc[1][0] += av.y * bv.x; acc[1][1] += av.y * bv.y; acc[1][2] += av.y * bv.z; acc[1][3] += av.y * bv.w;
            acc[2][0] += av.z * bv.x; acc[2][1] += av.z * bv.y; acc[2][2] += av.z * bv.z; acc[2][3] += av.z * bv.w;
            acc[3][0] += av.w * bv.x; acc[3][1] += av.w * bv.y; acc[3][2] += av.w * bv.z; acc[3][3] += av.w * bv.w;
        }
        __syncthreads();
    }
#pragma unroll
    for (int i = 0; i < 4; ++i) {
        const int m = m0 + (ty << 2) + i;
#pragma unroll
        for (int j = 0; j < 4; ++j) {
            const int n = n0 + (tx << 2) + j;
            float v = acc[i][j] + bias[n];
            if (MUL) v *= mulp[(size_t)m * N + n];
            if (RELU) v = fmaxf(v, 0.f);
            C[(size_t)m * N + n] = v;
        }
    }
}

// ======================= conv1: 5x5, CI=1, fused outer-product, relu+pool2
// out: NHWC bf16 (chunk, 100, 100, 64), per-sample stride = out_stride
__global__ __launch_bounds__(256) void conv1_kernel(
    const float* __restrict__ emb, const int* __restrict__ pair,
    const float* __restrict__ wgt, const float* __restrict__ bias,
    unsigned short* __restrict__ out, int n0, long out_stride)
{
    const int n = blockIdx.x;
    const int gn = n0 + n;
    const int co0 = blockIdx.y * 16;
    const int p = blockIdx.z * 256 + threadIdx.x;
    if (p >= 100 * 100) return;
    const int py = p / 100, px = p - py * 100;
    const int i0 = 2 * py - 2, j0 = 2 * px - 2;
    const float* oe = emb + (size_t)(pair[2 * gn + 0] + 1) * 200;
    const float* se = emb + (size_t)(pair[2 * gn + 1] + 1) * 200;
    float ov[6], sv[6];
#pragma unroll
    for (int t = 0; t < 6; ++t) {
        const int i = i0 + t, j = j0 + t;
        ov[t] = ((unsigned)i < 200u) ? oe[i] : 0.f;
        sv[t] = ((unsigned)j < 200u) ? se[j] : 0.f;
    }
    float xm[6][6];
#pragma unroll
    for (int r = 0; r < 6; ++r)
#pragma unroll
        for (int c = 0; c < 6; ++c) xm[r][c] = ov[r] * sv[c];
    unsigned short vals[16];
#pragma unroll 1
    for (int c = 0; c < 16; ++c) {
        const float* wc = wgt + (size_t)(co0 + c) * 25;
        float s0, s1, s2, s3;
        s0 = s1 = s2 = s3 = bias[co0 + c];
#pragma unroll
        for (int dy = 0; dy < 5; ++dy)
#pragma unroll
            for (int dx = 0; dx < 5; ++dx) {
                const float wv = wc[dy * 5 + dx];
                s0 += xm[dy][dx] * wv;
                s1 += xm[dy][dx + 1] * wv;
                s2 += xm[dy + 1][dx] * wv;
                s3 += xm[dy + 1][dx + 1] * wv;
            }
        const float v = 0.25f * (fmaxf(s0, 0.f) + fmaxf(s1, 0.f) + fmaxf(s2, 0.f) + fmaxf(s3, 0.f));
        vals[c] = f2bf(v);
    }
    unsigned short* op = out + (size_t)n * out_stride + (size_t)p * 64 + co0;
    *reinterpret_cast<s16x8*>(op)     = *reinterpret_cast<s16x8*>(&vals[0]);
    *reinterpret_cast<s16x8*>(op + 8) = *reinterpret_cast<s16x8*>(&vals[8]);
}

// ======= weight repack: OIHW f32 -> (co, dy, dx, ci) bf16 =======
__global__ __launch_bounds__(256) void repack_kernel(
    const float* __restrict__ w, unsigned short* __restrict__ o, int CO, int CI)
{
    const int idx = blockIdx.x * 256 + threadIdx.x;
    const int total = CO * CI * 9;
    if (idx >= total) return;
    const int co = idx / (CI * 9);
    const int rem = idx - co * (CI * 9);
    const int ci = rem / 9;
    const int k = rem - ci * 9;
    o[(size_t)co * (9 * CI) + (size_t)k * CI + ci] = f2bf(w[idx]);
}

// ======= implicit-GEMM MFMA 3x3 conv, pad=1, relu, NHWC bf16 =======
// in: (C, W, W, CI) bf16; wr: (CO, 9*CI) bf16 k-major (dy,dx,ci); out: (C, W, W, CO)
template<int CI, int W>
__global__ __launch_bounds__(256) void convmf_kernel(
    const unsigned short* __restrict__ in, const unsigned short* __restrict__ wr,
    const float* __restrict__ bias, unsigned short* __restrict__ out,
    int CO, long in_stride, long out_stride)
{
    constexpr int NPIX = W * W;
    constexpr int K = 9 * CI;
    constexpr int CLOG = (CI == 64) ? 6 : (CI == 128) ? 7 : 8;
    const int lane = threadIdx.x & 63;
    const int wid = threadIdx.x >> 6;
    const int wm = wid >> 1, wn = wid & 1;
    const int co_blk = blockIdx.y * 64;

    const unsigned short* inp = in + (size_t)blockIdx.z * in_stride;
    unsigned short* outp = out + (size_t)blockIdx.z * out_stride;

    const int p0 = blockIdx.x * 64 + wn * 32 + (lane & 15);
    const int p1 = p0 + 16;
    const bool v0 = p0 < NPIX, v1 = p1 < NPIX;
    const int pc0 = v0 ? p0 : NPIX - 1, pc1 = v1 ? p1 : NPIX - 1;
    const int py0 = pc0 / W, px0 = pc0 - py0 * W;
    const int py1 = pc1 / W, px1 = pc1 - py1 * W;
    const unsigned short* bp0 = inp + (size_t)(py0 * W + px0) * CI;
    const unsigned short* bp1 = inp + (size_t)(py1 * W + px1) * CI;

    const int kl = (lane >> 4) * 8;
    const unsigned short* wa = wr + (size_t)(co_blk + wm * 32 + (lane & 15)) * K + kl;

    f32x4 acc[2][2] = {};

    for (int k0 = 0; k0 < K; k0 += 32) {
        const int kk = k0 + kl;
        const int ci = kk & (CI - 1);
        const int dydx = kk >> CLOG;
        const int dy = (dydx * 11) >> 5;
        const int dx = dydx - dy * 3;
        const int koff = ((dy - 1) * W + (dx - 1)) * CI + ci;
        s16x8 a0 = *reinterpret_cast<const s16x8*>(wa + k0);
        s16x8 a1 = *reinterpret_cast<const s16x8*>(wa + (size_t)16 * K + k0);
        s16x8 b0 = {}, b1 = {};
        {
            const int iy = py0 + dy - 1, ix = px0 + dx - 1;
            if (v0 && (unsigned)iy < (unsigned)W && (unsigned)ix < (unsigned)W)
                b0 = *reinterpret_cast<const s16x8*>(bp0 + koff);
        }
        {
            const int iy = py1 + dy - 1, ix = px1 + dx - 1;
            if (v1 && (unsigned)iy < (unsigned)W && (unsigned)ix < (unsigned)W)
                b1 = *reinterpret_cast<const s16x8*>(bp1 + koff);
        }
        acc[0][0] = __builtin_amdgcn_mfma_f32_16x16x32_bf16(a0, b0, acc[0][0], 0, 0, 0);
        acc[0][1] = __builtin_amdgcn_mfma_f32_16x16x32_bf16(a0, b1, acc[0][1], 0, 0, 0);
        acc[1][0] = __builtin_amdgcn_mfma_f32_16x16x32_bf16(a1, b0, acc[1][0], 0, 0, 0);
        acc[1][1] = __builtin_amdgcn_mfma_f32_16x16x32_bf16(a1, b1, acc[1][1], 0, 0, 0);
    }

#pragma unroll
    for (int mf = 0; mf < 2; ++mf) {
        const int co = co_blk + wm * 32 + mf * 16 + (lane >> 4) * 4;
        float b0 = bias[co], b1 = bias[co + 1], b2 = bias[co + 2], b3 = bias[co + 3];
#pragma unroll
        for (int nf = 0; nf < 2; ++nf) {
            const int p = nf ? p1 : p0;
            const bool v = nf ? v1 : v0;
            if (!v) continue;
            f32x4 a = acc[mf][nf];
            unsigned short r[4];
            r[0] = f2bf(fmaxf(a.x + b0, 0.f));
            r[1] = f2bf(fmaxf(a.y + b1, 0.f));
            r[2] = f2bf(fmaxf(a.z + b2, 0.f));
            r[3] = f2bf(fmaxf(a.w + b3, 0.f));
            *reinterpret_cast<s16x4*>(outp + (size_t)p * CO + co) = *reinterpret_cast<s16x4*>(r);
        }
    }
}

// ======= 2x2 mean pool, NHWC bf16 =======
template<int OHW, int CO>
__global__ __launch_bounds__(256) void pool_kernel(
    const unsigned short* __restrict__ in, unsigned short* __restrict__ out,
    long in_stride, long out_stride)
{
    constexpr int W2 = OHW * 2;
    constexpr int C8 = CO / 8;
    constexpr int ITEMS = OHW * C8;
    const int n = blockIdx.x, y = blockIdx.y;
    const unsigned short* ip = in + (size_t)n * in_stride + (size_t)(2 * y) * W2 * CO;
    unsigned short* op = out + (size_t)n * out_stride + (size_t)y * OHW * CO;
    for (int it = threadIdx.x; it < ITEMS; it += 256) {
        const int x = it >> ((C8 == 16) ? 4 : 5);
        const int c0 = (it - x * C8) * 8;
        const unsigned short* q = ip + (size_t)(2 * x) * CO + c0;
        s16x8 a = *reinterpret_cast<const s16x8*>(q);
        s16x8 b = *reinterpret_cast<const s16x8*>(q + CO);
        s16x8 c = *reinterpret_cast<const s16x8*>(q + (size_t)W2 * CO);
        s16x8 d = *reinterpret_cast<const s16x8*>(q + (size_t)W2 * CO + CO);
        s16x8 r;
#pragma unroll
        for (int j = 0; j < 8; ++j)
            r[j] = (short)f2bf(0.25f * (bf2f((unsigned short)a[j]) + bf2f((unsigned short)b[j]) +
                                        bf2f((unsigned short)c[j]) + bf2f((unsigned short)d[j])));
        *reinterpret_cast<s16x8*>(op + (size_t)x * CO + c0) = r;
    }
}

// ======= global average pool over 625 pixels, NHWC bf16 -> f32 =======
__global__ __launch_bounds__(256) void gap_kernel(
    const unsigned short* __restrict__ in, float* __restrict__ gap,
    int n0, long in_stride)
{
    __shared__ float sm[4][512];
    const unsigned short* ip = in + (size_t)blockIdx.x * in_stride;
    const int g = threadIdx.x >> 6;
    const int c8 = threadIdx.x & 63;
    float s[8] = {};
    for (int p = g; p < 625; p += 4) {
        s16x8 v = *reinterpret_cast<const s16x8*>(ip + (size_t)p * 512 + c8 * 8);
#pragma unroll
        for (int j = 0; j < 8; ++j) s[j] += bf2f((unsigned short)v[j]);
    }
#pragma unroll
    for (int j = 0; j < 8; ++j) sm[g][c8 * 8 + j] = s[j];
    __syncthreads();
    if (g == 0) {
#pragma unroll
        for (int j = 0; j < 8; ++j) {
            const int ch = c8 * 8 + j;
            const float t = sm[0][ch] + sm[1][ch] + sm[2][ch] + sm[3][ch];
            gap[(size_t)(n0 + blockIdx.x) * 512 + ch] = t * (1.f / 625.f);
        }
    }
}

// ======= small fused kernels for the relation head =======
__global__ __launch_bounds__(256) void prod_kernel(
    const float* __restrict__ er, const int* __restrict__ pair, float* __restrict__ pr)
{
    const int r = blockIdx.x;
    const int p0 = pair[2 * r], p1 = pair[2 * r + 1];
    for (int i = threadIdx.x; i < 1024; i += 256) {
        const int src = (i < 512) ? p0 : p1;
        pr[(size_t)r * 1024 + i] = er[(size_t)src * 1024 + i];
    }
}

__global__ __launch_bounds__(256) void rcat_kernel(
    const float* __restrict__ prodr, const float* __restrict__ ef, float* __restrict__ rc)
{
    const int r = blockIdx.x;
    for (int i = threadIdx.x; i < 1536; i += 256) {
        float v;
        if (i < 512)       v = prodr[(size_t)r * 1024 + i];
        else if (i < 1024) v = ef[(size_t)r * 512 + (i - 512)];
        else               v = prodr[(size_t)r * 1024 + (i - 1024) + 512];
        rc[(size_t)r * 1536 + i] = v;
    }
}

__global__ __launch_bounds__(256) void cat8_kernel(
    const float* __restrict__ pwe, const float* __restrict__ un, float* __restrict__ cat)
{
    const int r = blockIdx.x;
    for (int i = threadIdx.x; i < 8192; i += 256) {
        cat[(size_t)r * 8192 + i] = (i < 4096) ? pwe[(size_t)r * 4096 + i]
                                               : un[(size_t)r * 4096 + (i - 4096)];
    }
}

__global__ __launch_bounds__(256) void reldist_kernel(
    const float* __restrict__ rf, const float* __restrict__ Wr, const float* __restrict__ br,
    const float* __restrict__ freq, const int* __restrict__ preds,
    const int* __restrict__ pair, float* __restrict__ out)
{
    const int idx = blockIdx.x * 256 + threadIdx.x;
    if (idx >= 128 * 51) return;
    const int r = idx / 51, j = idx - r * 51;
    const float* a = rf + (size_t)r * 512;
    float s = br[j];
    for (int k = 0; k < 512; ++k) s += a[k] * Wr[(size_t)k * 51 + j];
    const int c0 = preds[pair[2 * r]], c1 = preds[pair[2 * r + 1]];
    s += freq[((size_t)c0 * 151 + c1) * 51 + j];
    out[idx] = s;
}

// ===========================================================================
extern "C" void kernel_launch(void* const* d_in, const int* in_sizes, int n_in,
                              void* d_out, int out_size, void* d_ws, size_t ws_size,
                              hipStream_t stream)
{
    const float* obj_feats  = (const float*)d_in[0];
    const int*   obj_preds  = (const int*)  d_in[1];
    const int*   pair       = (const int*)  d_in[2];
    const float* unionf     = (const float*)d_in[3];
    const float* W_post_emb = (const float*)d_in[4];
    const float* b_post_emb = (const float*)d_in[5];
    const float* W_post_cat = (const float*)d_in[6];
    const float* b_post_cat = (const float*)d_in[7];
    const float* W_edge     = (const float*)d_in[8];
    const float* b_edge     = (const float*)d_in[9];
    const float* W_lin      = (const float*)d_in[10];
    const float* b_lin      = (const float*)d_in[11];
    const float* W_rel      = (const float*)d_in[12];
    const float* b_rel      = (const float*)d_in[13];
    const float* freq       = (const float*)d_in[14];
    const float* emb        = (const float*)d_in[15];
    const float* cw1 = (const float*)d_in[16]; const float* cb1 = (const float*)d_in[17];
    const float* cw2 = (const float*)d_in[18]; const float* cb2 = (const float*)d_in[19];
    const float* cw3 = (const float*)d_in[20]; const float* cb3 = (const float*)d_in[21];
    const float* cw4 = (const float*)d_in[22]; const float* cb4 = (const float*)d_in[23];
    const float* cw5 = (const float*)d_in[24]; const float* cb5 = (const float*)d_in[25];
    const float* cw6 = (const float*)d_in[26]; const float* cb6 = (const float*)d_in[27];
    const float* Ww1 = (const float*)d_in[28]; const float* bw1 = (const float*)d_in[29];
    const float* Ww2 = (const float*)d_in[30]; const float* bw2 = (const float*)d_in[31];
    float* out = (float*)d_out;

    // ---- workspace layout ----
    float* ws = (float*)d_ws;
    float* edge_rep   = ws;                       // 1024*1024
    float* prodr      = edge_rep + 1048576;       // 128*1024
    float* visual     = prodr + 131072;           // 128*4096
    float* edge_feats = visual + 524288;          // 128*512
    float* rcat       = edge_feats + 65536;       // 128*1536
    float* rel_feats  = rcat + 196608;            // 128*512
    float* gap        = rel_feats + 65536;        // 128*512
    float* x5         = gap + 65536;              // 128*384
    float* pwe        = x5 + 49152;               // 128*4096
    float* cat8       = pwe + 524288;             // 128*8192
    float* hbuf       = cat8 + 1048576;           // 128*512
    const size_t persist_f32 = 3784704ull;

    unsigned short* wsu = (unsigned short*)(ws + persist_f32);
    unsigned short* w2r = wsu;                    // 128*576
    unsigned short* w3r = w2r + 73728;            // 256*1152
    unsigned short* w4r = w3r + 294912;           // 512*2304
    unsigned short* actA = w4r + 1179648;

    int C = 128;
    const size_t base_bytes = persist_f32 * 4 + 1548288ull * 2;
    while (C > 1 && base_bytes + (size_t)C * 1920000ull * 2 > ws_size) C >>= 1;
    unsigned short* actB = actA + (size_t)C * 640000;   // conv outputs (<=1.28M el/sample)

    // ---- relation branch (f32) ----
    gemm_kernel<false,false,false><<<dim3(16,16),256,0,stream>>>(obj_feats, W_post_emb, b_post_emb, nullptr, edge_rep, 1024,1024,512);
    prod_kernel<<<dim3(128),256,0,stream>>>(edge_rep, pair, prodr);
    gemm_kernel<false,false,true ><<<dim3(2,64),256,0,stream>>>(prodr, W_post_cat, b_post_cat, unionf, visual, 128,4096,1024);
    gemm_kernel<false,true ,false><<<dim3(2,8),256,0,stream>>>(visual, W_edge, b_edge, nullptr, edge_feats, 128,512,4096);
    rcat_kernel<<<dim3(128),256,0,stream>>>(prodr, edge_feats, rcat);
    gemm_kernel<false,false,false><<<dim3(2,8),256,0,stream>>>(rcat, W_lin, b_lin, nullptr, rel_feats, 128,512,1536);
    reldist_kernel<<<dim3(26),256,0,stream>>>(rel_feats, W_rel, b_rel, freq, obj_preds, pair, out);

    // ---- weight repacks (bf16, k-major (dy,dx,ci)) ----
    repack_kernel<<<dim3((73728  + 255) / 256),256,0,stream>>>(cw2, w2r, 128, 64);
    repack_kernel<<<dim3((294912 + 255) / 256),256,0,stream>>>(cw3, w3r, 256, 128);
    repack_kernel<<<dim3((1179648+ 255) / 256),256,0,stream>>>(cw4, w4r, 512, 256);

    // ---- conv chain (MFMA implicit GEMM, NHWC bf16, chunked over batch) ----
    for (int n0 = 0; n0 < 128; n0 += C) {
        conv1_kernel<<<dim3(C,4,40),256,0,stream>>>(emb, pair, cw1, cb1, actA, n0, 640000);
        convmf_kernel<64,100><<<dim3(157,2,C),256,0,stream>>>(actA, w2r, cb2, actB, 128, 640000, 1280000);
        pool_kernel<50,128><<<dim3(C,50),256,0,stream>>>(actB, actA, 1280000, 640000);
        convmf_kernel<128,50><<<dim3(40,4,C),256,0,stream>>>(actA, w3r, cb3, actB, 256, 640000, 1280000);
        pool_kernel<25,256><<<dim3(C,25),256,0,stream>>>(actB, actA, 1280000, 640000);
        convmf_kernel<256,25><<<dim3(10,8,C),256,0,stream>>>(actA, w4r, cb4, actB, 512, 640000, 1280000);
        gap_kernel<<<dim3(C),256,0,stream>>>(actB, gap, n0, 1280000);
    }

    // ---- conv tail (1x1 convs as GEMMs, B^T layout, f32) ----
    gemm_kernel<true ,true ,false><<<dim3(2,6),256,0,stream>>>(gap, cw5, cb5, nullptr, x5, 128,384,512);
    gemm_kernel<true ,false,false><<<dim3(2,64),256,0,stream>>>(x5, cw6, cb6, nullptr, pwe, 128,4096,384);

    // ---- union head ----
    cat8_kernel<<<dim3(128),256,0,stream>>>(pwe, unionf, cat8);
    gemm_kernel<false,true ,false><<<dim3(2,8),256,0,stream>>>(cat8, Ww1, bw1, nullptr, hbuf, 128,512,8192);
    gemm_kernel<false,true ,false><<<dim3(2,64),256,0,stream>>>(hbuf, Ww2, bw2, nullptr, out + 6528, 128,4096,512);
}

// Round 3
// 3469.608 us; speedup vs baseline: 2.9579x; 1.5551x over previous
//
#include <hip/hip_runtime.h>
#include <hip/hip_bf16.h>

// ---------------------------------------------------------------------------
// HID=512 POOL=4096 N_OBJ_CLS=151 N_REL_CLS=51 EMB=200 N_OBJ=1024 N_REL=128
// ---------------------------------------------------------------------------

typedef __attribute__((ext_vector_type(8))) short  s16x8;
typedef __attribute__((ext_vector_type(4))) short  s16x4;
typedef __attribute__((ext_vector_type(4))) float  f32x4;

__device__ inline unsigned short f2bf(float f) {
    unsigned u = __builtin_bit_cast(unsigned, f);
    u = (u + 0x7FFF + ((u >> 16) & 1)) >> 16;
    return (unsigned short)u;
}
__device__ inline float bf2f(unsigned short s) {
    unsigned u = ((unsigned)s) << 16;
    return __builtin_bit_cast(float, u);
}

// ======================= generic f32 GEMM (64x64 tile) ======================
template<bool BT, bool RELU, bool MUL>
__global__ __launch_bounds__(256) void gemm_kernel(
    const float* __restrict__ A, const float* __restrict__ B,
    const float* __restrict__ bias, const float* __restrict__ mulp,
    float* __restrict__ C, int M, int N, int K)
{
    __shared__ float As[16][68];
    __shared__ float Bs[16][68];
    const int m0 = blockIdx.x * 64, n0 = blockIdx.y * 64;
    const int tid = threadIdx.x;
    const int ty = tid >> 4, tx = tid & 15;
    float acc[4][4] = {};
    for (int k0 = 0; k0 < K; k0 += 16) {
        {
            const int m = tid >> 2, kq = (tid & 3) << 2;
            const float4 a = *reinterpret_cast<const float4*>(A + (size_t)(m0 + m) * K + k0 + kq);
            As[kq + 0][m] = a.x; As[kq + 1][m] = a.y; As[kq + 2][m] = a.z; As[kq + 3][m] = a.w;
        }
        if (!BT) {
            const int kk = tid >> 4, nq = (tid & 15) << 2;
            const float4 b = *reinterpret_cast<const float4*>(B + (size_t)(k0 + kk) * N + n0 + nq);
            *reinterpret_cast<float4*>(&Bs[kk][nq]) = b;
        } else {
            const int nn = tid >> 2, kq = (tid & 3) << 2;
            const float4 b = *reinterpret_cast<const float4*>(B + (size_t)(n0 + nn) * K + k0 + kq);
            Bs[kq + 0][nn] = b.x; Bs[kq + 1][nn] = b.y; Bs[kq + 2][nn] = b.z; Bs[kq + 3][nn] = b.w;
        }
        __syncthreads();
#pragma unroll
        for (int k = 0; k < 16; ++k) {
            const float4 av = *reinterpret_cast<const float4*>(&As[k][ty << 2]);
            const float4 bv = *reinterpret_cast<const float4*>(&Bs[k][tx << 2]);
            acc[0][0] += av.x * bv.x; acc[0][1] += av.x * bv.y; acc[0][2] += av.x * bv.z; acc[0][3] += av.x * bv.w;
            acc[1][0] += av.y * bv.x; acc[1][1] += av.y * bv.y; acc[1][2] += av.y * bv.z; acc[1][3] += av.y * bv.w;
            acc[2][0] += av.z * bv.x; acc[2][1] += av.z * bv.y; acc[2][2] += av.z * bv.z; acc[2][3] += av.z * bv.w;
            acc[3][0] += av.w * bv.x; acc[3][1] += av.w * bv.y; acc[3][2] += av.w * bv.z; acc[3][3] += av.w * bv.w;
        }
        __syncthreads();
    }
#pragma unroll
    for (int i = 0; i < 4; ++i) {
        const int m = m0 + (ty << 2) + i;
#pragma unroll
        for (int j = 0; j < 4; ++j) {
            const int n = n0 + (tx << 2) + j;
            float v = acc[i][j] + bias[n];
            if (MUL) v *= mulp[(size_t)m * N + n];
            if (RELU) v = fmaxf(v, 0.f);
            C[(size_t)m * N + n] = v;
        }
    }
}

// ======================= conv1: separable 5x5 via rank-1 input ==============
// x[i,j] = oe[i]*se[j] ; out(co,i,j) = sum_dy oe[i-2+dy] * r[co,dy,j]
// where r[co,dy,j] = sum_dx w[co,dy,dx]*se[j-2+dx]  (precomputed in LDS).
// Fused relu + 2x2 meanpool; out NHWC bf16 (n,100,100,64). 8 co per block.
__global__ __launch_bounds__(256) void conv1_kernel(
    const float* __restrict__ emb, const int* __restrict__ pair,
    const float* __restrict__ wgt, const float* __restrict__ bias,
    unsigned short* __restrict__ out, int n0, long out_stride)
{
    __shared__ float soe[200], sse[200];
    __shared__ float r[8][5][204];
    const int n = blockIdx.x, gn = n0 + n;
    const int co0 = blockIdx.y * 8;
    const int tid = threadIdx.x;
    const float* oe = emb + (size_t)(pair[2 * gn + 0] + 1) * 200;
    const float* se = emb + (size_t)(pair[2 * gn + 1] + 1) * 200;
    if (tid < 200) { soe[tid] = oe[tid]; sse[tid] = se[tid]; }
    __syncthreads();
    // phase 1: row-convolve se with each (co, dy) 1x5 filter: 8*5*200 items
    for (int it = tid; it < 8000; it += 256) {
        const int c = it / 1000;
        const int rem = it - c * 1000;
        const int dy = rem / 200;
        const int j = rem - dy * 200;
        const float* w = wgt + (size_t)(co0 + c) * 25 + dy * 5;
        float s = 0.f;
#pragma unroll
        for (int dx = 0; dx < 5; ++dx) {
            const int jj = j + dx - 2;
            if ((unsigned)jj < 200u) s += w[dx] * sse[jj];
        }
        r[c][dy][j] = s;
    }
    __syncthreads();
    float bz[8];
#pragma unroll
    for (int c = 0; c < 8; ++c) bz[c] = bias[co0 + c];
    for (int p = tid; p < 10000; p += 256) {
        const int py = p / 100, px = p - py * 100;
        const int i0 = 2 * py - 2, j0 = 2 * px;
        float ov[6];
#pragma unroll
        for (int t = 0; t < 6; ++t) {
            const int ii = i0 + t;
            ov[t] = ((unsigned)ii < 200u) ? soe[ii] : 0.f;
        }
        unsigned short vals[8];
#pragma unroll
        for (int c = 0; c < 8; ++c) {
            float s00 = bz[c], s01 = bz[c], s10 = bz[c], s11 = bz[c];
#pragma unroll
            for (int dy = 0; dy < 5; ++dy) {
                const float2 rv = *reinterpret_cast<const float2*>(&r[c][dy][j0]);
                s00 += ov[dy]     * rv.x; s01 += ov[dy]     * rv.y;
                s10 += ov[dy + 1] * rv.x; s11 += ov[dy + 1] * rv.y;
            }
            vals[c] = f2bf(0.25f * (fmaxf(s00, 0.f) + fmaxf(s01, 0.f) +
                                    fmaxf(s10, 0.f) + fmaxf(s11, 0.f)));
        }
        *reinterpret_cast<s16x8*>(out + (size_t)n * out_stride + (size_t)p * 64 + co0) =
            *reinterpret_cast<s16x8*>(vals);
    }
}

// ======= weight repack: OIHW f32 -> (co, dy, dx, ci) bf16 =======
__global__ __launch_bounds__(256) void repack_kernel(
    const float* __restrict__ w, unsigned short* __restrict__ o, int CO, int CI)
{
    const int idx = blockIdx.x * 256 + threadIdx.x;
    const int total = CO * CI * 9;
    if (idx >= total) return;
    const int co = idx / (CI * 9);
    const int rem = idx - co * (CI * 9);
    const int ci = rem / 9;
    const int k = rem - ci * 9;
    o[(size_t)co * (9 * CI) + (size_t)k * CI + ci] = f2bf(w[idx]);
}

// ======= implicit-GEMM MFMA 3x3 conv, pad=1, relu, NHWC bf16 =======
// 4x4 register tile per wave: block = 128co x 128px, wave = 64co x 64px.
template<int CI, int W>
__global__ __launch_bounds__(256) void convmf_kernel(
    const unsigned short* __restrict__ in, const unsigned short* __restrict__ wr,
    const float* __restrict__ bias, unsigned short* __restrict__ out,
    int CO, long in_stride, long out_stride)
{
    constexpr int NPIX = W * W;
    constexpr int K = 9 * CI;
    constexpr int CLOG = (CI == 64) ? 6 : (CI == 128) ? 7 : 8;
    const int lane = threadIdx.x & 63;
    const int wid = threadIdx.x >> 6;
    const int wm = wid >> 1, wn = wid & 1;
    const int co_blk = blockIdx.y * 128;

    const unsigned short* inp = in + (size_t)blockIdx.z * in_stride;
    unsigned short* outp = out + (size_t)blockIdx.z * out_stride;

    int p[4], py[4], px[4];
    bool v[4];
    const unsigned short* bp[4];
#pragma unroll
    for (int nf = 0; nf < 4; ++nf) {
        p[nf] = blockIdx.x * 128 + wn * 64 + nf * 16 + (lane & 15);
        v[nf] = p[nf] < NPIX;
        const int pc = v[nf] ? p[nf] : 0;
        py[nf] = pc / W; px[nf] = pc - py[nf] * W;
        bp[nf] = inp + (size_t)pc * CI;
    }
    const int kl = (lane >> 4) * 8;
    const unsigned short* wa[4];
#pragma unroll
    for (int mf = 0; mf < 4; ++mf)
        wa[mf] = wr + (size_t)(co_blk + wm * 64 + mf * 16 + (lane & 15)) * K + kl;

    f32x4 acc[4][4] = {};

    for (int k0 = 0; k0 < K; k0 += 32) {
        const int kk = k0 + kl;
        const int ci = kk & (CI - 1);
        const int dydx = kk >> CLOG;          // wave-uniform within a step
        const int dy = (dydx * 11) >> 5;
        const int dx = dydx - dy * 3;
        const int koff = ((dy - 1) * W + (dx - 1)) * CI + ci;
        s16x8 a[4], b[4];
#pragma unroll
        for (int mf = 0; mf < 4; ++mf)
            a[mf] = *reinterpret_cast<const s16x8*>(wa[mf] + k0);
#pragma unroll
        for (int nf = 0; nf < 4; ++nf) {
            const int iy = py[nf] + dy - 1, ix = px[nf] + dx - 1;
            b[nf] = {};
            if (v[nf] && (unsigned)iy < (unsigned)W && (unsigned)ix < (unsigned)W)
                b[nf] = *reinterpret_cast<const s16x8*>(bp[nf] + koff);
        }
#pragma unroll
        for (int mf = 0; mf < 4; ++mf)
#pragma unroll
            for (int nf = 0; nf < 4; ++nf)
                acc[mf][nf] = __builtin_amdgcn_mfma_f32_16x16x32_bf16(a[mf], b[nf], acc[mf][nf], 0, 0, 0);
    }

#pragma unroll
    for (int mf = 0; mf < 4; ++mf) {
        const int co = co_blk + wm * 64 + mf * 16 + (lane >> 4) * 4;
        const float b0 = bias[co], b1 = bias[co + 1], b2 = bias[co + 2], b3 = bias[co + 3];
#pragma unroll
        for (int nf = 0; nf < 4; ++nf) {
            if (!v[nf]) continue;
            f32x4 a = acc[mf][nf];
            unsigned short r[4];
            r[0] = f2bf(fmaxf(a.x + b0, 0.f));
            r[1] = f2bf(fmaxf(a.y + b1, 0.f));
            r[2] = f2bf(fmaxf(a.z + b2, 0.f));
            r[3] = f2bf(fmaxf(a.w + b3, 0.f));
            *reinterpret_cast<s16x4*>(outp + (size_t)p[nf] * CO + co) = *reinterpret_cast<s16x4*>(r);
        }
    }
}

// ======= 2x2 mean pool, NHWC bf16 =======
template<int OHW, int CO>
__global__ __launch_bounds__(256) void pool_kernel(
    const unsigned short* __restrict__ in, unsigned short* __restrict__ out,
    long in_stride, long out_stride)
{
    constexpr int W2 = OHW * 2;
    constexpr int C8 = CO / 8;
    constexpr int ITEMS = OHW * C8;
    const int n = blockIdx.x, y = blockIdx.y;
    const unsigned short* ip = in + (size_t)n * in_stride + (size_t)(2 * y) * W2 * CO;
    unsigned short* op = out + (size_t)n * out_stride + (size_t)y * OHW * CO;
    for (int it = threadIdx.x; it < ITEMS; it += 256) {
        const int x = it >> ((C8 == 16) ? 4 : 5);
        const int c0 = (it - x * C8) * 8;
        const unsigned short* q = ip + (size_t)(2 * x) * CO + c0;
        s16x8 a = *reinterpret_cast<const s16x8*>(q);
        s16x8 b = *reinterpret_cast<const s16x8*>(q + CO);
        s16x8 c = *reinterpret_cast<const s16x8*>(q + (size_t)W2 * CO);
        s16x8 d = *reinterpret_cast<const s16x8*>(q + (size_t)W2 * CO + CO);
        s16x8 r;
#pragma unroll
        for (int j = 0; j < 8; ++j)
            r[j] = (short)f2bf(0.25f * (bf2f((unsigned short)a[j]) + bf2f((unsigned short)b[j]) +
                                        bf2f((unsigned short)c[j]) + bf2f((unsigned short)d[j])));
        *reinterpret_cast<s16x8*>(op + (size_t)x * CO + c0) = r;
    }
}

// ======= global average pool over 625 pixels, NHWC bf16 -> f32 =======
__global__ __launch_bounds__(256) void gap_kernel(
    const unsigned short* __restrict__ in, float* __restrict__ gap,
    int n0, long in_stride)
{
    __shared__ float sm[4][512];
    const unsigned short* ip = in + (size_t)blockIdx.x * in_stride;
    const int g = threadIdx.x >> 6;
    const int c8 = threadIdx.x & 63;
    float s[8] = {};
    for (int p = g; p < 625; p += 4) {
        s16x8 v = *reinterpret_cast<const s16x8*>(ip + (size_t)p * 512 + c8 * 8);
#pragma unroll
        for (int j = 0; j < 8; ++j) s[j] += bf2f((unsigned short)v[j]);
    }
#pragma unroll
    for (int j = 0; j < 8; ++j) sm[g][c8 * 8 + j] = s[j];
    __syncthreads();
    if (g == 0) {
#pragma unroll
        for (int j = 0; j < 8; ++j) {
            const int ch = c8 * 8 + j;
            const float t = sm[0][ch] + sm[1][ch] + sm[2][ch] + sm[3][ch];
            gap[(size_t)(n0 + blockIdx.x) * 512 + ch] = t * (1.f / 625.f);
        }
    }
}

// ======= small fused kernels for the relation head =======
__global__ __launch_bounds__(256) void prod_kernel(
    const float* __restrict__ er, const int* __restrict__ pair, float* __restrict__ pr)
{
    const int r = blockIdx.x;
    const int p0 = pair[2 * r], p1 = pair[2 * r + 1];
    for (int i = threadIdx.x; i < 1024; i += 256) {
        const int src = (i < 512) ? p0 : p1;
        pr[(size_t)r * 1024 + i] = er[(size_t)src * 1024 + i];
    }
}

__global__ __launch_bounds__(256) void rcat_kernel(
    const float* __restrict__ prodr, const float* __restrict__ ef, float* __restrict__ rc)
{
    const int r = blockIdx.x;
    for (int i = threadIdx.x; i < 1536; i += 256) {
        float v;
        if (i < 512)       v = prodr[(size_t)r * 1024 + i];
        else if (i < 1024) v = ef[(size_t)r * 512 + (i - 512)];
        else               v = prodr[(size_t)r * 1024 + (i - 1024) + 512];
        rc[(size_t)r * 1536 + i] = v;
    }
}

__global__ __launch_bounds__(256) void cat8_kernel(
    const float* __restrict__ pwe, const float* __restrict__ un, float* __restrict__ cat)
{
    const int r = blockIdx.x;
    for (int i = threadIdx.x; i < 8192; i += 256) {
        cat[(size_t)r * 8192 + i] = (i < 4096) ? pwe[(size_t)r * 4096 + i]
                                               : un[(size_t)r * 4096 + (i - 4096)];
    }
}

__global__ __launch_bounds__(256) void reldist_kernel(
    const float* __restrict__ rf, const float* __restrict__ Wr, const float* __restrict__ br,
    const float* __restrict__ freq, const int* __restrict__ preds,
    const int* __restrict__ pair, float* __restrict__ out)
{
    const int idx = blockIdx.x * 256 + threadIdx.x;
    if (idx >= 128 * 51) return;
    const int r = idx / 51, j = idx - r * 51;
    const float* a = rf + (size_t)r * 512;
    float s = br[j];
    for (int k = 0; k < 512; ++k) s += a[k] * Wr[(size_t)k * 51 + j];
    const int c0 = preds[pair[2 * r]], c1 = preds[pair[2 * r + 1]];
    s += freq[((size_t)c0 * 151 + c1) * 51 + j];
    out[idx] = s;
}

// ===========================================================================
extern "C" void kernel_launch(void* const* d_in, const int* in_sizes, int n_in,
                              void* d_out, int out_size, void* d_ws, size_t ws_size,
                              hipStream_t stream)
{
    const float* obj_feats  = (const float*)d_in[0];
    const int*   obj_preds  = (const int*)  d_in[1];
    const int*   pair       = (const int*)  d_in[2];
    const float* unionf     = (const float*)d_in[3];
    const float* W_post_emb = (const float*)d_in[4];
    const float* b_post_emb = (const float*)d_in[5];
    const float* W_post_cat = (const float*)d_in[6];
    const float* b_post_cat = (const float*)d_in[7];
    const float* W_edge     = (const float*)d_in[8];
    const float* b_edge     = (const float*)d_in[9];
    const float* W_lin      = (const float*)d_in[10];
    const float* b_lin      = (const float*)d_in[11];
    const float* W_rel      = (const float*)d_in[12];
    const float* b_rel      = (const float*)d_in[13];
    const float* freq       = (const float*)d_in[14];
    const float* emb        = (const float*)d_in[15];
    const float* cw1 = (const float*)d_in[16]; const float* cb1 = (const float*)d_in[17];
    const float* cw2 = (const float*)d_in[18]; const float* cb2 = (const float*)d_in[19];
    const float* cw3 = (const float*)d_in[20]; const float* cb3 = (const float*)d_in[21];
    const float* cw4 = (const float*)d_in[22]; const float* cb4 = (const float*)d_in[23];
    const float* cw5 = (const float*)d_in[24]; const float* cb5 = (const float*)d_in[25];
    const float* cw6 = (const float*)d_in[26]; const float* cb6 = (const float*)d_in[27];
    const float* Ww1 = (const float*)d_in[28]; const float* bw1 = (const float*)d_in[29];
    const float* Ww2 = (const float*)d_in[30]; const float* bw2 = (const float*)d_in[31];
    float* out = (float*)d_out;

    // ---- workspace layout ----
    float* ws = (float*)d_ws;
    float* edge_rep   = ws;                       // 1024*1024
    float* prodr      = edge_rep + 1048576;       // 128*1024
    float* visual     = prodr + 131072;           // 128*4096
    float* edge_feats = visual + 524288;          // 128*512
    float* rcat       = edge_feats + 65536;       // 128*1536
    float* rel_feats  = rcat + 196608;            // 128*512
    float* gap        = rel_feats + 65536;        // 128*512
    float* x5         = gap + 65536;              // 128*384
    float* pwe        = x5 + 49152;               // 128*4096
    float* cat8       = pwe + 524288;             // 128*8192
    float* hbuf       = cat8 + 1048576;           // 128*512
    const size_t persist_f32 = 3784704ull;

    unsigned short* wsu = (unsigned short*)(ws + persist_f32);
    unsigned short* w2r = wsu;                    // 128*576
    unsigned short* w3r = w2r + 73728;            // 256*1152
    unsigned short* w4r = w3r + 294912;           // 512*2304
    unsigned short* actA = w4r + 1179648;

    int C = 128;
    const size_t base_bytes = persist_f32 * 4 + 1548288ull * 2;
    while (C > 1 && base_bytes + (size_t)C * 1920000ull * 2 > ws_size) C >>= 1;
    unsigned short* actB = actA + (size_t)C * 640000;

    // ---- relation branch (f32) ----
    gemm_kernel<false,false,false><<<dim3(16,16),256,0,stream>>>(obj_feats, W_post_emb, b_post_emb, nullptr, edge_rep, 1024,1024,512);
    prod_kernel<<<dim3(128),256,0,stream>>>(edge_rep, pair, prodr);
    gemm_kernel<false,false,true ><<<dim3(2,64),256,0,stream>>>(prodr, W_post_cat, b_post_cat, unionf, visual, 128,4096,1024);
    gemm_kernel<false,true ,false><<<dim3(2,8),256,0,stream>>>(visual, W_edge, b_edge, nullptr, edge_feats, 128,512,4096);
    rcat_kernel<<<dim3(128),256,0,stream>>>(prodr, edge_feats, rcat);
    gemm_kernel<false,false,false><<<dim3(2,8),256,0,stream>>>(rcat, W_lin, b_lin, nullptr, rel_feats, 128,512,1536);
    reldist_kernel<<<dim3(26),256,0,stream>>>(rel_feats, W_rel, b_rel, freq, obj_preds, pair, out);

    // ---- weight repacks (bf16, k-major (dy,dx,ci)) ----
    repack_kernel<<<dim3((73728  + 255) / 256),256,0,stream>>>(cw2, w2r, 128, 64);
    repack_kernel<<<dim3((294912 + 255) / 256),256,0,stream>>>(cw3, w3r, 256, 128);
    repack_kernel<<<dim3((1179648+ 255) / 256),256,0,stream>>>(cw4, w4r, 512, 256);

    // ---- conv chain (MFMA implicit GEMM, NHWC bf16, chunked over batch) ----
    for (int n0 = 0; n0 < 128; n0 += C) {
        conv1_kernel<<<dim3(C,8),256,0,stream>>>(emb, pair, cw1, cb1, actA, n0, 640000);
        convmf_kernel<64,100><<<dim3(79,1,C),256,0,stream>>>(actA, w2r, cb2, actB, 128, 640000, 1280000);
        pool_kernel<50,128><<<dim3(C,50),256,0,stream>>>(actB, actA, 1280000, 640000);
        convmf_kernel<128,50><<<dim3(20,2,C),256,0,stream>>>(actA, w3r, cb3, actB, 256, 640000, 1280000);
        pool_kernel<25,256><<<dim3(C,25),256,0,stream>>>(actB, actA, 1280000, 640000);
        convmf_kernel<256,25><<<dim3(5,4,C),256,0,stream>>>(actA, w4r, cb4, actB, 512, 640000, 1280000);
        gap_kernel<<<dim3(C),256,0,stream>>>(actB, gap, n0, 1280000);
    }

    // ---- conv tail (1x1 convs as GEMMs, B^T layout, f32) ----
    gemm_kernel<true ,true ,false><<<dim3(2,6),256,0,stream>>>(gap, cw5, cb5, nullptr, x5, 128,384,512);
    gemm_kernel<true ,false,false><<<dim3(2,64),256,0,stream>>>(x5, cw6, cb6, nullptr, pwe, 128,4096,384);

    // ---- union head ----
    cat8_kernel<<<dim3(128),256,0,stream>>>(pwe, unionf, cat8);
    gemm_kernel<false,true ,false><<<dim3(2,8),256,0,stream>>>(cat8, Ww1, bw1, nullptr, hbuf, 128,512,8192);
    gemm_kernel<false,true ,false><<<dim3(2,64),256,0,stream>>>(hbuf, Ww2, bw2, nullptr, out + 6528, 128,4096,512);
}

// Round 4
// 2939.847 us; speedup vs baseline: 3.4909x; 1.1802x over previous
//
#include <hip/hip_runtime.h>
#include <hip/hip_bf16.h>

// ---------------------------------------------------------------------------
// HID=512 POOL=4096 N_OBJ_CLS=151 N_REL_CLS=51 EMB=200 N_OBJ=1024 N_REL=128
// ---------------------------------------------------------------------------

typedef __attribute__((ext_vector_type(8))) short  s16x8;
typedef __attribute__((ext_vector_type(4))) short  s16x4;
typedef __attribute__((ext_vector_type(4))) float  f32x4;

__device__ inline unsigned short f2bf(float f) {
    unsigned u = __builtin_bit_cast(unsigned, f);
    u = (u + 0x7FFF + ((u >> 16) & 1)) >> 16;
    return (unsigned short)u;
}
__device__ inline float bf2f(unsigned short s) {
    unsigned u = ((unsigned)s) << 16;
    return __builtin_bit_cast(float, u);
}

// ======================= generic f32 GEMM (64x64 tile) ======================
template<bool BT, bool RELU, bool MUL>
__global__ __launch_bounds__(256) void gemm_kernel(
    const float* __restrict__ A, const float* __restrict__ B,
    const float* __restrict__ bias, const float* __restrict__ mulp,
    float* __restrict__ C, int M, int N, int K)
{
    __shared__ float As[16][68];
    __shared__ float Bs[16][68];
    const int m0 = blockIdx.x * 64, n0 = blockIdx.y * 64;
    const int tid = threadIdx.x;
    const int ty = tid >> 4, tx = tid & 15;
    float acc[4][4] = {};
    for (int k0 = 0; k0 < K; k0 += 16) {
        {
            const int m = tid >> 2, kq = (tid & 3) << 2;
            const float4 a = *reinterpret_cast<const float4*>(A + (size_t)(m0 + m) * K + k0 + kq);
            As[kq + 0][m] = a.x; As[kq + 1][m] = a.y; As[kq + 2][m] = a.z; As[kq + 3][m] = a.w;
        }
        if (!BT) {
            const int kk = tid >> 4, nq = (tid & 15) << 2;
            const float4 b = *reinterpret_cast<const float4*>(B + (size_t)(k0 + kk) * N + n0 + nq);
            *reinterpret_cast<float4*>(&Bs[kk][nq]) = b;
        } else {
            const int nn = tid >> 2, kq = (tid & 3) << 2;
            const float4 b = *reinterpret_cast<const float4*>(B + (size_t)(n0 + nn) * K + k0 + kq);
            Bs[kq + 0][nn] = b.x; Bs[kq + 1][nn] = b.y; Bs[kq + 2][nn] = b.z; Bs[kq + 3][nn] = b.w;
        }
        __syncthreads();
#pragma unroll
        for (int k = 0; k < 16; ++k) {
            const float4 av = *reinterpret_cast<const float4*>(&As[k][ty << 2]);
            const float4 bv = *reinterpret_cast<const float4*>(&Bs[k][tx << 2]);
            acc[0][0] += av.x * bv.x; acc[0][1] += av.x * bv.y; acc[0][2] += av.x * bv.z; acc[0][3] += av.x * bv.w;
            acc[1][0] += av.y * bv.x; acc[1][1] += av.y * bv.y; acc[1][2] += av.y * bv.z; acc[1][3] += av.y * bv.w;
            acc[2][0] += av.z * bv.x; acc[2][1] += av.z * bv.y; acc[2][2] += av.z * bv.z; acc[2][3] += av.z * bv.w;
            acc[3][0] += av.w * bv.x; acc[3][1] += av.w * bv.y; acc[3][2] += av.w * bv.z; acc[3][3] += av.w * bv.w;
        }
        __syncthreads();
    }
#pragma unroll
    for (int i = 0; i < 4; ++i) {
        const int m = m0 + (ty << 2) + i;
#pragma unroll
        for (int j = 0; j < 4; ++j) {
            const int n = n0 + (tx << 2) + j;
            float v = acc[i][j] + bias[n];
            if (MUL) v *= mulp[(size_t)m * N + n];
            if (RELU) v = fmaxf(v, 0.f);
            C[(size_t)m * N + n] = v;
        }
    }
}

// =================== split-K f32 GEMM: partials + reduce ====================
// grid (M/64, N/64, KS); each block covers K-chunk [z*kchunk, (z+1)*kchunk)
template<bool BT>
__global__ __launch_bounds__(256) void gemmsk_kernel(
    const float* __restrict__ A, const float* __restrict__ B,
    float* __restrict__ part, int M, int N, int K, int kchunk)
{
    __shared__ float As[16][68];
    __shared__ float Bs[16][68];
    const int m0 = blockIdx.x * 64, n0 = blockIdx.y * 64;
    const int kbeg = blockIdx.z * kchunk, kend = kbeg + kchunk;
    const int tid = threadIdx.x;
    const int ty = tid >> 4, tx = tid & 15;
    float acc[4][4] = {};
    for (int k0 = kbeg; k0 < kend; k0 += 16) {
        {
            const int m = tid >> 2, kq = (tid & 3) << 2;
            const float4 a = *reinterpret_cast<const float4*>(A + (size_t)(m0 + m) * K + k0 + kq);
            As[kq + 0][m] = a.x; As[kq + 1][m] = a.y; As[kq + 2][m] = a.z; As[kq + 3][m] = a.w;
        }
        if (!BT) {
            const int kk = tid >> 4, nq = (tid & 15) << 2;
            const float4 b = *reinterpret_cast<const float4*>(B + (size_t)(k0 + kk) * N + n0 + nq);
            *reinterpret_cast<float4*>(&Bs[kk][nq]) = b;
        } else {
            const int nn = tid >> 2, kq = (tid & 3) << 2;
            const float4 b = *reinterpret_cast<const float4*>(B + (size_t)(n0 + nn) * K + k0 + kq);
            Bs[kq + 0][nn] = b.x; Bs[kq + 1][nn] = b.y; Bs[kq + 2][nn] = b.z; Bs[kq + 3][nn] = b.w;
        }
        __syncthreads();
#pragma unroll
        for (int k = 0; k < 16; ++k) {
            const float4 av = *reinterpret_cast<const float4*>(&As[k][ty << 2]);
            const float4 bv = *reinterpret_cast<const float4*>(&Bs[k][tx << 2]);
            acc[0][0] += av.x * bv.x; acc[0][1] += av.x * bv.y; acc[0][2] += av.x * bv.z; acc[0][3] += av.x * bv.w;
            acc[1][0] += av.y * bv.x; acc[1][1] += av.y * bv.y; acc[1][2] += av.y * bv.z; acc[1][3] += av.y * bv.w;
            acc[2][0] += av.z * bv.x; acc[2][1] += av.z * bv.y; acc[2][2] += av.z * bv.z; acc[2][3] += av.z * bv.w;
            acc[3][0] += av.w * bv.x; acc[3][1] += av.w * bv.y; acc[3][2] += av.w * bv.z; acc[3][3] += av.w * bv.w;
        }
        __syncthreads();
    }
    float* pp = part + (size_t)blockIdx.z * M * N;
#pragma unroll
    for (int i = 0; i < 4; ++i) {
        const int m = m0 + (ty << 2) + i;
#pragma unroll
        for (int j = 0; j < 4; ++j)
            pp[(size_t)m * N + n0 + (tx << 2) + j] = acc[i][j];
    }
}

template<bool RELU, bool MUL>
__global__ __launch_bounds__(256) void reduce_kernel(
    const float* __restrict__ part, const float* __restrict__ bias,
    const float* __restrict__ mulp, float* __restrict__ C, int M, int N, int KS)
{
    const int idx = blockIdx.x * 256 + threadIdx.x;
    if (idx >= M * N) return;
    const int n = idx % N;
    float s = bias[n];
    for (int ks = 0; ks < KS; ++ks) s += part[(size_t)ks * M * N + idx];
    if (MUL) s *= mulp[idx];
    if (RELU) s = fmaxf(s, 0.f);
    C[idx] = s;
}

// ======================= conv1: separable 5x5 via rank-1 input ==============
__global__ __launch_bounds__(256) void conv1_kernel(
    const float* __restrict__ emb, const int* __restrict__ pair,
    const float* __restrict__ wgt, const float* __restrict__ bias,
    unsigned short* __restrict__ out, int n0, long out_stride)
{
    __shared__ float soe[200], sse[200];
    __shared__ float r[8][5][204];
    const int n = blockIdx.x, gn = n0 + n;
    const int co0 = blockIdx.y * 8;
    const int tid = threadIdx.x;
    const float* oe = emb + (size_t)(pair[2 * gn + 0] + 1) * 200;
    const float* se = emb + (size_t)(pair[2 * gn + 1] + 1) * 200;
    if (tid < 200) { soe[tid] = oe[tid]; sse[tid] = se[tid]; }
    __syncthreads();
    for (int it = tid; it < 8000; it += 256) {
        const int c = it / 1000;
        const int rem = it - c * 1000;
        const int dy = rem / 200;
        const int j = rem - dy * 200;
        const float* w = wgt + (size_t)(co0 + c) * 25 + dy * 5;
        float s = 0.f;
#pragma unroll
        for (int dx = 0; dx < 5; ++dx) {
            const int jj = j + dx - 2;
            if ((unsigned)jj < 200u) s += w[dx] * sse[jj];
        }
        r[c][dy][j] = s;
    }
    __syncthreads();
    float bz[8];
#pragma unroll
    for (int c = 0; c < 8; ++c) bz[c] = bias[co0 + c];
    for (int p = tid; p < 10000; p += 256) {
        const int py = p / 100, px = p - py * 100;
        const int i0 = 2 * py - 2, j0 = 2 * px;
        float ov[6];
#pragma unroll
        for (int t = 0; t < 6; ++t) {
            const int ii = i0 + t;
            ov[t] = ((unsigned)ii < 200u) ? soe[ii] : 0.f;
        }
        unsigned short vals[8];
#pragma unroll
        for (int c = 0; c < 8; ++c) {
            float s00 = bz[c], s01 = bz[c], s10 = bz[c], s11 = bz[c];
#pragma unroll
            for (int dy = 0; dy < 5; ++dy) {
                const float2 rv = *reinterpret_cast<const float2*>(&r[c][dy][j0]);
                s00 += ov[dy]     * rv.x; s01 += ov[dy]     * rv.y;
                s10 += ov[dy + 1] * rv.x; s11 += ov[dy + 1] * rv.y;
            }
            vals[c] = f2bf(0.25f * (fmaxf(s00, 0.f) + fmaxf(s01, 0.f) +
                                    fmaxf(s10, 0.f) + fmaxf(s11, 0.f)));
        }
        *reinterpret_cast<s16x8*>(out + (size_t)n * out_stride + (size_t)p * 64 + co0) =
            *reinterpret_cast<s16x8*>(vals);
    }
}

// ======= weight repack: OIHW f32 -> (co, dy, dx, ci) bf16 =======
__global__ __launch_bounds__(256) void repack_kernel(
    const float* __restrict__ w, unsigned short* __restrict__ o, int CO, int CI)
{
    const int idx = blockIdx.x * 256 + threadIdx.x;
    const int total = CO * CI * 9;
    if (idx >= total) return;
    const int co = idx / (CI * 9);
    const int rem = idx - co * (CI * 9);
    const int ci = rem / 9;
    const int k = rem - ci * 9;
    o[(size_t)co * (9 * CI) + (size_t)k * CI + ci] = f2bf(w[idx]);
}

// ======= implicit-GEMM MFMA 3x3 conv, pad=1, relu, NHWC bf16 =======
template<int CI, int W>
__global__ __launch_bounds__(256) void convmf_kernel(
    const unsigned short* __restrict__ in, const unsigned short* __restrict__ wr,
    const float* __restrict__ bias, unsigned short* __restrict__ out,
    int CO, long in_stride, long out_stride)
{
    constexpr int NPIX = W * W;
    constexpr int K = 9 * CI;
    constexpr int CLOG = (CI == 64) ? 6 : (CI == 128) ? 7 : 8;
    const int lane = threadIdx.x & 63;
    const int wid = threadIdx.x >> 6;
    const int wm = wid >> 1, wn = wid & 1;
    const int co_blk = blockIdx.y * 128;

    const unsigned short* inp = in + (size_t)blockIdx.z * in_stride;
    unsigned short* outp = out + (size_t)blockIdx.z * out_stride;

    int p[4], py[4], px[4];
    bool v[4];
    const unsigned short* bp[4];
#pragma unroll
    for (int nf = 0; nf < 4; ++nf) {
        p[nf] = blockIdx.x * 128 + wn * 64 + nf * 16 + (lane & 15);
        v[nf] = p[nf] < NPIX;
        const int pc = v[nf] ? p[nf] : 0;
        py[nf] = pc / W; px[nf] = pc - py[nf] * W;
        bp[nf] = inp + (size_t)pc * CI;
    }
    const int kl = (lane >> 4) * 8;
    const unsigned short* wa[4];
#pragma unroll
    for (int mf = 0; mf < 4; ++mf)
        wa[mf] = wr + (size_t)(co_blk + wm * 64 + mf * 16 + (lane & 15)) * K + kl;

    f32x4 acc[4][4] = {};

    for (int k0 = 0; k0 < K; k0 += 32) {
        const int kk = k0 + kl;
        const int ci = kk & (CI - 1);
        const int dydx = kk >> CLOG;
        const int dy = (dydx * 11) >> 5;
        const int dx = dydx - dy * 3;
        const int koff = ((dy - 1) * W + (dx - 1)) * CI + ci;
        s16x8 a[4], b[4];
#pragma unroll
        for (int mf = 0; mf < 4; ++mf)
            a[mf] = *reinterpret_cast<const s16x8*>(wa[mf] + k0);
#pragma unroll
        for (int nf = 0; nf < 4; ++nf) {
            const int iy = py[nf] + dy - 1, ix = px[nf] + dx - 1;
            b[nf] = {};
            if (v[nf] && (unsigned)iy < (unsigned)W && (unsigned)ix < (unsigned)W)
                b[nf] = *reinterpret_cast<const s16x8*>(bp[nf] + koff);
        }
#pragma unroll
        for (int mf = 0; mf < 4; ++mf)
#pragma unroll
            for (int nf = 0; nf < 4; ++nf)
                acc[mf][nf] = __builtin_amdgcn_mfma_f32_16x16x32_bf16(a[mf], b[nf], acc[mf][nf], 0, 0, 0);
    }

#pragma unroll
    for (int mf = 0; mf < 4; ++mf) {
        const int co = co_blk + wm * 64 + mf * 16 + (lane >> 4) * 4;
        const float b0 = bias[co], b1 = bias[co + 1], b2 = bias[co + 2], b3 = bias[co + 3];
#pragma unroll
        for (int nf = 0; nf < 4; ++nf) {
            if (!v[nf]) continue;
            f32x4 a = acc[mf][nf];
            unsigned short r[4];
            r[0] = f2bf(fmaxf(a.x + b0, 0.f));
            r[1] = f2bf(fmaxf(a.y + b1, 0.f));
            r[2] = f2bf(fmaxf(a.z + b2, 0.f));
            r[3] = f2bf(fmaxf(a.w + b3, 0.f));
            *reinterpret_cast<s16x4*>(outp + (size_t)p[nf] * CO + co) = *reinterpret_cast<s16x4*>(r);
        }
    }
}

// ======= 2x2 mean pool, NHWC bf16 =======
template<int OHW, int CO>
__global__ __launch_bounds__(256) void pool_kernel(
    const unsigned short* __restrict__ in, unsigned short* __restrict__ out,
    long in_stride, long out_stride)
{
    constexpr int W2 = OHW * 2;
    constexpr int C8 = CO / 8;
    constexpr int ITEMS = OHW * C8;
    const int n = blockIdx.x, y = blockIdx.y;
    const unsigned short* ip = in + (size_t)n * in_stride + (size_t)(2 * y) * W2 * CO;
    unsigned short* op = out + (size_t)n * out_stride + (size_t)y * OHW * CO;
    for (int it = threadIdx.x; it < ITEMS; it += 256) {
        const int x = it >> ((C8 == 16) ? 4 : 5);
        const int c0 = (it - x * C8) * 8;
        const unsigned short* q = ip + (size_t)(2 * x) * CO + c0;
        s16x8 a = *reinterpret_cast<const s16x8*>(q);
        s16x8 b = *reinterpret_cast<const s16x8*>(q + CO);
        s16x8 c = *reinterpret_cast<const s16x8*>(q + (size_t)W2 * CO);
        s16x8 d = *reinterpret_cast<const s16x8*>(q + (size_t)W2 * CO + CO);
        s16x8 r;
#pragma unroll
        for (int j = 0; j < 8; ++j)
            r[j] = (short)f2bf(0.25f * (bf2f((unsigned short)a[j]) + bf2f((unsigned short)b[j]) +
                                        bf2f((unsigned short)c[j]) + bf2f((unsigned short)d[j])));
        *reinterpret_cast<s16x8*>(op + (size_t)x * CO + c0) = r;
    }
}

// ======= global average pool over 625 pixels, NHWC bf16 -> f32 =======
__global__ __launch_bounds__(256) void gap_kernel(
    const unsigned short* __restrict__ in, float* __restrict__ gap,
    int n0, long in_stride)
{
    __shared__ float sm[4][512];
    const unsigned short* ip = in + (size_t)blockIdx.x * in_stride;
    const int g = threadIdx.x >> 6;
    const int c8 = threadIdx.x & 63;
    float s[8] = {};
    for (int p = g; p < 625; p += 4) {
        s16x8 v = *reinterpret_cast<const s16x8*>(ip + (size_t)p * 512 + c8 * 8);
#pragma unroll
        for (int j = 0; j < 8; ++j) s[j] += bf2f((unsigned short)v[j]);
    }
#pragma unroll
    for (int j = 0; j < 8; ++j) sm[g][c8 * 8 + j] = s[j];
    __syncthreads();
    if (g == 0) {
#pragma unroll
        for (int j = 0; j < 8; ++j) {
            const int ch = c8 * 8 + j;
            const float t = sm[0][ch] + sm[1][ch] + sm[2][ch] + sm[3][ch];
            gap[(size_t)(n0 + blockIdx.x) * 512 + ch] = t * (1.f / 625.f);
        }
    }
}

// ======= small fused kernels for the relation head =======
__global__ __launch_bounds__(256) void prod_kernel(
    const float* __restrict__ er, const int* __restrict__ pair, float* __restrict__ pr)
{
    const int r = blockIdx.x;
    const int p0 = pair[2 * r], p1 = pair[2 * r + 1];
    for (int i = threadIdx.x; i < 1024; i += 256) {
        const int src = (i < 512) ? p0 : p1;
        pr[(size_t)r * 1024 + i] = er[(size_t)src * 1024 + i];
    }
}

__global__ __launch_bounds__(256) void rcat_kernel(
    const float* __restrict__ prodr, const float* __restrict__ ef, float* __restrict__ rc)
{
    const int r = blockIdx.x;
    for (int i = threadIdx.x; i < 1536; i += 256) {
        float v;
        if (i < 512)       v = prodr[(size_t)r * 1024 + i];
        else if (i < 1024) v = ef[(size_t)r * 512 + (i - 512)];
        else               v = prodr[(size_t)r * 1024 + (i - 1024) + 512];
        rc[(size_t)r * 1536 + i] = v;
    }
}

__global__ __launch_bounds__(256) void cat8_kernel(
    const float* __restrict__ pwe, const float* __restrict__ un, float* __restrict__ cat)
{
    const int r = blockIdx.x;
    for (int i = threadIdx.x; i < 8192; i += 256) {
        cat[(size_t)r * 8192 + i] = (i < 4096) ? pwe[(size_t)r * 4096 + i]
                                               : un[(size_t)r * 4096 + (i - 4096)];
    }
}

__global__ __launch_bounds__(256) void reldist_kernel(
    const float* __restrict__ rf, const float* __restrict__ Wr, const float* __restrict__ br,
    const float* __restrict__ freq, const int* __restrict__ preds,
    const int* __restrict__ pair, float* __restrict__ out)
{
    const int idx = blockIdx.x * 256 + threadIdx.x;
    if (idx >= 128 * 51) return;
    const int r = idx / 51, j = idx - r * 51;
    const float* a = rf + (size_t)r * 512;
    float s = br[j];
    for (int k = 0; k < 512; ++k) s += a[k] * Wr[(size_t)k * 51 + j];
    const int c0 = preds[pair[2 * r]], c1 = preds[pair[2 * r + 1]];
    s += freq[((size_t)c0 * 151 + c1) * 51 + j];
    out[idx] = s;
}

// ===========================================================================
extern "C" void kernel_launch(void* const* d_in, const int* in_sizes, int n_in,
                              void* d_out, int out_size, void* d_ws, size_t ws_size,
                              hipStream_t stream)
{
    const float* obj_feats  = (const float*)d_in[0];
    const int*   obj_preds  = (const int*)  d_in[1];
    const int*   pair       = (const int*)  d_in[2];
    const float* unionf     = (const float*)d_in[3];
    const float* W_post_emb = (const float*)d_in[4];
    const float* b_post_emb = (const float*)d_in[5];
    const float* W_post_cat = (const float*)d_in[6];
    const float* b_post_cat = (const float*)d_in[7];
    const float* W_edge     = (const float*)d_in[8];
    const float* b_edge     = (const float*)d_in[9];
    const float* W_lin      = (const float*)d_in[10];
    const float* b_lin      = (const float*)d_in[11];
    const float* W_rel      = (const float*)d_in[12];
    const float* b_rel      = (const float*)d_in[13];
    const float* freq       = (const float*)d_in[14];
    const float* emb        = (const float*)d_in[15];
    const float* cw1 = (const float*)d_in[16]; const float* cb1 = (const float*)d_in[17];
    const float* cw2 = (const float*)d_in[18]; const float* cb2 = (const float*)d_in[19];
    const float* cw3 = (const float*)d_in[20]; const float* cb3 = (const float*)d_in[21];
    const float* cw4 = (const float*)d_in[22]; const float* cb4 = (const float*)d_in[23];
    const float* cw5 = (const float*)d_in[24]; const float* cb5 = (const float*)d_in[25];
    const float* cw6 = (const float*)d_in[26]; const float* cb6 = (const float*)d_in[27];
    const float* Ww1 = (const float*)d_in[28]; const float* bw1 = (const float*)d_in[29];
    const float* Ww2 = (const float*)d_in[30]; const float* bw2 = (const float*)d_in[31];
    float* out = (float*)d_out;

    // ---- workspace layout (floats) ----
    float* ws = (float*)d_ws;
    float* edge_rep   = ws;                       // 1024*1024
    float* prodr      = edge_rep + 1048576;       // 128*1024
    float* visual     = prodr + 131072;           // 128*4096
    float* edge_feats = visual + 524288;          // 128*512
    float* rcat       = edge_feats + 65536;       // 128*1536
    float* rel_feats  = rcat + 196608;            // 128*512
    float* gap        = rel_feats + 65536;        // 128*512
    float* x5         = gap + 65536;              // 128*384
    float* pwe        = x5 + 49152;               // 128*4096
    float* cat8       = pwe + 524288;             // 128*8192
    float* hbuf       = cat8 + 1048576;           // 128*512
    float* part       = hbuf + 65536;             // 2097152 (split-K partials)
    const size_t persist_f32 = 3784704ull + 2097152ull;

    unsigned short* wsu = (unsigned short*)(ws + persist_f32);
    unsigned short* w2r = wsu;                    // 128*576
    unsigned short* w3r = w2r + 73728;            // 256*1152
    unsigned short* w4r = w3r + 294912;           // 512*2304
    unsigned short* actA = w4r + 1179648;

    int C = 128;
    const size_t base_bytes = persist_f32 * 4 + 1548288ull * 2;
    while (C > 1 && base_bytes + (size_t)C * 1920000ull * 2 > ws_size) C >>= 1;
    unsigned short* actB = actA + (size_t)C * 640000;

    // ---- relation branch ----
    gemm_kernel<false,false,false><<<dim3(16,16),256,0,stream>>>(obj_feats, W_post_emb, b_post_emb, nullptr, edge_rep, 1024,1024,512);
    prod_kernel<<<dim3(128),256,0,stream>>>(edge_rep, pair, prodr);
    // visual = (prodr @ W_post_cat + b) * unionf   [split-K: KS=4, chunk 256]
    gemmsk_kernel<false><<<dim3(2,64,4),256,0,stream>>>(prodr, W_post_cat, part, 128,4096,1024, 256);
    reduce_kernel<false,true ><<<dim3(2048),256,0,stream>>>(part, b_post_cat, unionf, visual, 128,4096,4);
    // edge_feats = relu(visual @ W_edge + b)       [KS=16, chunk 256]
    gemmsk_kernel<false><<<dim3(2,8,16),256,0,stream>>>(visual, W_edge, part, 128,512,4096, 256);
    reduce_kernel<true ,false><<<dim3(256),256,0,stream>>>(part, b_edge, nullptr, edge_feats, 128,512,16);
    rcat_kernel<<<dim3(128),256,0,stream>>>(prodr, edge_feats, rcat);
    // rel_feats = rcat @ W_lin + b                 [KS=8, chunk 192]
    gemmsk_kernel<false><<<dim3(2,8,8),256,0,stream>>>(rcat, W_lin, part, 128,512,1536, 192);
    reduce_kernel<false,false><<<dim3(256),256,0,stream>>>(part, b_lin, nullptr, rel_feats, 128,512,8);
    reldist_kernel<<<dim3(26),256,0,stream>>>(rel_feats, W_rel, b_rel, freq, obj_preds, pair, out);

    // ---- weight repacks (bf16, k-major (dy,dx,ci)) ----
    repack_kernel<<<dim3((73728  + 255) / 256),256,0,stream>>>(cw2, w2r, 128, 64);
    repack_kernel<<<dim3((294912 + 255) / 256),256,0,stream>>>(cw3, w3r, 256, 128);
    repack_kernel<<<dim3((1179648+ 255) / 256),256,0,stream>>>(cw4, w4r, 512, 256);

    // ---- conv chain (MFMA implicit GEMM, NHWC bf16, chunked over batch) ----
    for (int n0 = 0; n0 < 128; n0 += C) {
        conv1_kernel<<<dim3(C,8),256,0,stream>>>(emb, pair, cw1, cb1, actA, n0, 640000);
        convmf_kernel<64,100><<<dim3(79,1,C),256,0,stream>>>(actA, w2r, cb2, actB, 128, 640000, 1280000);
        pool_kernel<50,128><<<dim3(C,50),256,0,stream>>>(actB, actA, 1280000, 640000);
        convmf_kernel<128,50><<<dim3(20,2,C),256,0,stream>>>(actA, w3r, cb3, actB, 256, 640000, 1280000);
        pool_kernel<25,256><<<dim3(C,25),256,0,stream>>>(actB, actA, 1280000, 640000);
        convmf_kernel<256,25><<<dim3(5,4,C),256,0,stream>>>(actA, w4r, cb4, actB, 512, 640000, 1280000);
        gap_kernel<<<dim3(C),256,0,stream>>>(actB, gap, n0, 1280000);
    }

    // ---- conv tail (1x1 convs as GEMMs, B^T layout) ----
    // x5 = relu(gap @ cw5^T + b)                  [KS=8, chunk 64]
    gemmsk_kernel<true ><<<dim3(2,6,8),256,0,stream>>>(gap, cw5, part, 128,384,512, 64);
    reduce_kernel<true ,false><<<dim3(192),256,0,stream>>>(part, cb5, nullptr, x5, 128,384,8);
    // pwe = x5 @ cw6^T + b                        [KS=4, chunk 96]
    gemmsk_kernel<true ><<<dim3(2,64,4),256,0,stream>>>(x5, cw6, part, 128,4096,384, 96);
    reduce_kernel<false,false><<<dim3(2048),256,0,stream>>>(part, cb6, nullptr, pwe, 128,4096,4);

    // ---- union head ----
    cat8_kernel<<<dim3(128),256,0,stream>>>(pwe, unionf, cat8);
    // hbuf = relu(cat8 @ Ww1 + b)                 [KS=32, chunk 256]
    gemmsk_kernel<false><<<dim3(2,8,32),256,0,stream>>>(cat8, Ww1, part, 128,512,8192, 256);
    reduce_kernel<true ,false><<<dim3(256),256,0,stream>>>(part, bw1, nullptr, hbuf, 128,512,32);
    // union_out = relu(hbuf @ Ww2 + b)            [KS=4, chunk 128]
    gemmsk_kernel<false><<<dim3(2,64,4),256,0,stream>>>(hbuf, Ww2, part, 128,4096,512, 128);
    reduce_kernel<true ,false><<<dim3(2048),256,0,stream>>>(part, bw2, nullptr, out + 6528, 128,4096,4);
}

// Round 5
// 1687.315 us; speedup vs baseline: 6.0823x; 1.7423x over previous
//
#include <hip/hip_runtime.h>
#include <hip/hip_bf16.h>

// ---------------------------------------------------------------------------
// HID=512 POOL=4096 N_OBJ_CLS=151 N_REL_CLS=51 EMB=200 N_OBJ=1024 N_REL=128
// ---------------------------------------------------------------------------

typedef __attribute__((ext_vector_type(8))) short  s16x8;
typedef __attribute__((ext_vector_type(4))) short  s16x4;
typedef __attribute__((ext_vector_type(4))) float  f32x4;

__device__ inline unsigned short f2bf(float f) {
    unsigned u = __builtin_bit_cast(unsigned, f);
    u = (u + 0x7FFF + ((u >> 16) & 1)) >> 16;
    return (unsigned short)u;
}
__device__ inline float bf2f(unsigned short s) {
    unsigned u = ((unsigned)s) << 16;
    return __builtin_bit_cast(float, u);
}

// ======================= generic f32 GEMM (64x64 tile) ======================
template<bool BT, bool RELU, bool MUL>
__global__ __launch_bounds__(256) void gemm_kernel(
    const float* __restrict__ A, const float* __restrict__ B,
    const float* __restrict__ bias, const float* __restrict__ mulp,
    float* __restrict__ C, int M, int N, int K)
{
    __shared__ float As[16][68];
    __shared__ float Bs[16][68];
    const int m0 = blockIdx.x * 64, n0 = blockIdx.y * 64;
    const int tid = threadIdx.x;
    const int ty = tid >> 4, tx = tid & 15;
    float acc[4][4] = {};
    for (int k0 = 0; k0 < K; k0 += 16) {
        {
            const int m = tid >> 2, kq = (tid & 3) << 2;
            const float4 a = *reinterpret_cast<const float4*>(A + (size_t)(m0 + m) * K + k0 + kq);
            As[kq + 0][m] = a.x; As[kq + 1][m] = a.y; As[kq + 2][m] = a.z; As[kq + 3][m] = a.w;
        }
        if (!BT) {
            const int kk = tid >> 4, nq = (tid & 15) << 2;
            const float4 b = *reinterpret_cast<const float4*>(B + (size_t)(k0 + kk) * N + n0 + nq);
            *reinterpret_cast<float4*>(&Bs[kk][nq]) = b;
        } else {
            const int nn = tid >> 2, kq = (tid & 3) << 2;
            const float4 b = *reinterpret_cast<const float4*>(B + (size_t)(n0 + nn) * K + k0 + kq);
            Bs[kq + 0][nn] = b.x; Bs[kq + 1][nn] = b.y; Bs[kq + 2][nn] = b.z; Bs[kq + 3][nn] = b.w;
        }
        __syncthreads();
#pragma unroll
        for (int k = 0; k < 16; ++k) {
            const float4 av = *reinterpret_cast<const float4*>(&As[k][ty << 2]);
            const float4 bv = *reinterpret_cast<const float4*>(&Bs[k][tx << 2]);
            acc[0][0] += av.x * bv.x; acc[0][1] += av.x * bv.y; acc[0][2] += av.x * bv.z; acc[0][3] += av.x * bv.w;
            acc[1][0] += av.y * bv.x; acc[1][1] += av.y * bv.y; acc[1][2] += av.y * bv.z; acc[1][3] += av.y * bv.w;
            acc[2][0] += av.z * bv.x; acc[2][1] += av.z * bv.y; acc[2][2] += av.z * bv.z; acc[2][3] += av.z * bv.w;
            acc[3][0] += av.w * bv.x; acc[3][1] += av.w * bv.y; acc[3][2] += av.w * bv.z; acc[3][3] += av.w * bv.w;
        }
        __syncthreads();
    }
#pragma unroll
    for (int i = 0; i < 4; ++i) {
        const int m = m0 + (ty << 2) + i;
#pragma unroll
        for (int j = 0; j < 4; ++j) {
            const int n = n0 + (tx << 2) + j;
            float v = acc[i][j] + bias[n];
            if (MUL) v *= mulp[(size_t)m * N + n];
            if (RELU) v = fmaxf(v, 0.f);
            C[(size_t)m * N + n] = v;
        }
    }
}

// =================== split-K f32 GEMM: partials + reduce ====================
template<bool BT>
__global__ __launch_bounds__(256) void gemmsk_kernel(
    const float* __restrict__ A, const float* __restrict__ B,
    float* __restrict__ part, int M, int N, int K, int kchunk)
{
    __shared__ float As[16][68];
    __shared__ float Bs[16][68];
    const int m0 = blockIdx.x * 64, n0 = blockIdx.y * 64;
    const int kbeg = blockIdx.z * kchunk, kend = kbeg + kchunk;
    const int tid = threadIdx.x;
    const int ty = tid >> 4, tx = tid & 15;
    float acc[4][4] = {};
    for (int k0 = kbeg; k0 < kend; k0 += 16) {
        {
            const int m = tid >> 2, kq = (tid & 3) << 2;
            const float4 a = *reinterpret_cast<const float4*>(A + (size_t)(m0 + m) * K + k0 + kq);
            As[kq + 0][m] = a.x; As[kq + 1][m] = a.y; As[kq + 2][m] = a.z; As[kq + 3][m] = a.w;
        }
        if (!BT) {
            const int kk = tid >> 4, nq = (tid & 15) << 2;
            const float4 b = *reinterpret_cast<const float4*>(B + (size_t)(k0 + kk) * N + n0 + nq);
            *reinterpret_cast<float4*>(&Bs[kk][nq]) = b;
        } else {
            const int nn = tid >> 2, kq = (tid & 3) << 2;
            const float4 b = *reinterpret_cast<const float4*>(B + (size_t)(n0 + nn) * K + k0 + kq);
            Bs[kq + 0][nn] = b.x; Bs[kq + 1][nn] = b.y; Bs[kq + 2][nn] = b.z; Bs[kq + 3][nn] = b.w;
        }
        __syncthreads();
#pragma unroll
        for (int k = 0; k < 16; ++k) {
            const float4 av = *reinterpret_cast<const float4*>(&As[k][ty << 2]);
            const float4 bv = *reinterpret_cast<const float4*>(&Bs[k][tx << 2]);
            acc[0][0] += av.x * bv.x; acc[0][1] += av.x * bv.y; acc[0][2] += av.x * bv.z; acc[0][3] += av.x * bv.w;
            acc[1][0] += av.y * bv.x; acc[1][1] += av.y * bv.y; acc[1][2] += av.y * bv.z; acc[1][3] += av.y * bv.w;
            acc[2][0] += av.z * bv.x; acc[2][1] += av.z * bv.y; acc[2][2] += av.z * bv.z; acc[2][3] += av.z * bv.w;
            acc[3][0] += av.w * bv.x; acc[3][1] += av.w * bv.y; acc[3][2] += av.w * bv.z; acc[3][3] += av.w * bv.w;
        }
        __syncthreads();
    }
    float* pp = part + (size_t)blockIdx.z * M * N;
#pragma unroll
    for (int i = 0; i < 4; ++i) {
        const int m = m0 + (ty << 2) + i;
#pragma unroll
        for (int j = 0; j < 4; ++j)
            pp[(size_t)m * N + n0 + (tx << 2) + j] = acc[i][j];
    }
}

template<bool RELU, bool MUL>
__global__ __launch_bounds__(256) void reduce_kernel(
    const float* __restrict__ part, const float* __restrict__ bias,
    const float* __restrict__ mulp, float* __restrict__ C, int M, int N, int KS)
{
    const int idx = blockIdx.x * 256 + threadIdx.x;
    if (idx >= M * N) return;
    const int n = idx % N;
    float s = bias[n];
    for (int ks = 0; ks < KS; ++ks) s += part[(size_t)ks * M * N + idx];
    if (MUL) s *= mulp[idx];
    if (RELU) s = fmaxf(s, 0.f);
    C[idx] = s;
}

// ======================= conv1: separable 5x5 via rank-1 input ==============
__global__ __launch_bounds__(256) void conv1_kernel(
    const float* __restrict__ emb, const int* __restrict__ pair,
    const float* __restrict__ wgt, const float* __restrict__ bias,
    unsigned short* __restrict__ out, int n0, long out_stride)
{
    __shared__ float soe[200], sse[200];
    __shared__ float r[8][5][204];
    const int n = blockIdx.x, gn = n0 + n;
    const int co0 = blockIdx.y * 8;
    const int tid = threadIdx.x;
    const float* oe = emb + (size_t)(pair[2 * gn + 0] + 1) * 200;
    const float* se = emb + (size_t)(pair[2 * gn + 1] + 1) * 200;
    if (tid < 200) { soe[tid] = oe[tid]; sse[tid] = se[tid]; }
    __syncthreads();
    for (int it = tid; it < 8000; it += 256) {
        const int c = it / 1000;
        const int rem = it - c * 1000;
        const int dy = rem / 200;
        const int j = rem - dy * 200;
        const float* w = wgt + (size_t)(co0 + c) * 25 + dy * 5;
        float s = 0.f;
#pragma unroll
        for (int dx = 0; dx < 5; ++dx) {
            const int jj = j + dx - 2;
            if ((unsigned)jj < 200u) s += w[dx] * sse[jj];
        }
        r[c][dy][j] = s;
    }
    __syncthreads();
    float bz[8];
#pragma unroll
    for (int c = 0; c < 8; ++c) bz[c] = bias[co0 + c];
    for (int p = tid; p < 10000; p += 256) {
        const int py = p / 100, px = p - py * 100;
        const int i0 = 2 * py - 2, j0 = 2 * px;
        float ov[6];
#pragma unroll
        for (int t = 0; t < 6; ++t) {
            const int ii = i0 + t;
            ov[t] = ((unsigned)ii < 200u) ? soe[ii] : 0.f;
        }
        unsigned short vals[8];
#pragma unroll
        for (int c = 0; c < 8; ++c) {
            float s00 = bz[c], s01 = bz[c], s10 = bz[c], s11 = bz[c];
#pragma unroll
            for (int dy = 0; dy < 5; ++dy) {
                const float2 rv = *reinterpret_cast<const float2*>(&r[c][dy][j0]);
                s00 += ov[dy]     * rv.x; s01 += ov[dy]     * rv.y;
                s10 += ov[dy + 1] * rv.x; s11 += ov[dy + 1] * rv.y;
            }
            vals[c] = f2bf(0.25f * (fmaxf(s00, 0.f) + fmaxf(s01, 0.f) +
                                    fmaxf(s10, 0.f) + fmaxf(s11, 0.f)));
        }
        *reinterpret_cast<s16x8*>(out + (size_t)n * out_stride + (size_t)p * 64 + co0) =
            *reinterpret_cast<s16x8*>(vals);
    }
}

// ======= weight repack: OIHW f32 -> MFMA A-fragment-contiguous bf16 =======
// layout: [g = co/16][t = k-step][lane][8]  where lane&15 = co%16,
// kk = t*32 + (lane>>4)*8 + e, ci = kk & (CI-1), dydx = kk >> CLOG.
__global__ __launch_bounds__(256) void frepack_kernel(
    const float* __restrict__ w, unsigned short* __restrict__ o,
    int CO, int CI, int NSTEP, int CLOG)
{
    const int id = blockIdx.x * 256 + threadIdx.x;
    const int total = (CO >> 4) * NSTEP * 64;
    if (id >= total) return;
    const int lane = id & 63;
    const int gt = id >> 6;
    const int t = gt % NSTEP, g = gt / NSTEP;
    const int co = g * 16 + (lane & 15);
    unsigned short r[8];
#pragma unroll
    for (int e = 0; e < 8; ++e) {
        const int kk = t * 32 + ((lane >> 4) << 3) + e;
        const int ci = kk & (CI - 1);
        const int dydx = kk >> CLOG;
        const int dy = dydx / 3, dx = dydx - dy * 3;
        r[e] = f2bf(w[((size_t)(co * CI + ci) * 3 + dy) * 3 + dx]);
    }
    *reinterpret_cast<s16x8*>(o + (size_t)id * 8) = *reinterpret_cast<s16x8*>(r);
}

// ======= LDS-staged implicit-GEMM MFMA 3x3 conv, pad=1, relu, NHWC bf16 =====
// Block: CO_BLK co x PX_BLK px. Input strip staged in LDS (XOR-swizzled),
// K-loop barrier-free; weights read as contiguous pre-packed fragments.
template<int CI, int W, int CO_BLK, int PX_BLK, int WM, int WN>
__global__ __launch_bounds__(256) void convlds_kernel(
    const unsigned short* __restrict__ in, const unsigned short* __restrict__ wf,
    const float* __restrict__ bias, unsigned short* __restrict__ out,
    int CO, long in_stride, long out_stride)
{
    constexpr int NPIX = W * W;
    constexpr int K = 9 * CI;
    constexpr int NSTEP = K / 32;
    constexpr int NC = CI / 8;                      // 16B chunks per pixel
    constexpr int NCL = (NC == 8) ? 3 : (NC == 16) ? 4 : 5;
    constexpr int CLOG = (CI == 64) ? 6 : (CI == 128) ? 7 : 8;
    constexpr int STAGE_PX = PX_BLK + 2 * W + 2;
    constexpr int TOT16 = STAGE_PX * NC;
    constexpr int WCO = CO_BLK / WM;                // 64
    constexpr int WPX = PX_BLK / WN;                // 64
    __shared__ unsigned short lds[STAGE_PX * CI + 8];

    const int tid = threadIdx.x;
    const unsigned short* inp = in + (size_t)blockIdx.z * in_stride;
    const int p_base = blockIdx.x * PX_BLK;
    const int q0 = p_base - (W + 1);

    // ---- stage input strip (clamped; borders handled by read predication) ----
    for (int i = tid; i < TOT16; i += 256) {
        const int s = i >> NCL;
        const int c = i & (NC - 1);
        int q = q0 + s;
        q = q < 0 ? 0 : (q >= NPIX ? NPIX - 1 : q);
        s16x8 v = *reinterpret_cast<const s16x8*>(inp + (size_t)q * CI + c * 8);
        const int perm = c ^ (s & (NC - 1));
        *reinterpret_cast<s16x8*>(&lds[(s * NC + perm) * 8]) = v;
    }
    if (tid == 0) *reinterpret_cast<s16x8*>(&lds[STAGE_PX * CI]) = s16x8{};
    __syncthreads();

    const int lane = tid & 63, wid = tid >> 6;
    const int wm = wid % WM, wn = wid / WM;
    const int lhi = lane >> 4, llo = lane & 15;
    const int g0 = (blockIdx.y * CO_BLK + wm * WCO) >> 4;

    const unsigned short* pa[4];
#pragma unroll
    for (int mf = 0; mf < 4; ++mf)
        pa[mf] = wf + ((size_t)(g0 + mf) * NSTEP * 64 + lane) * 8;

    int sb[4], py[4], px[4];
    bool vp[4];
#pragma unroll
    for (int nf = 0; nf < 4; ++nf) {
        const int p = p_base + wn * WPX + nf * 16 + llo;
        vp[nf] = p < NPIX;
        py[nf] = p / W; px[nf] = p - py[nf] * W;
        sb[nf] = p - q0;
    }

    f32x4 acc[4][4] = {};
    for (int t = 0; t < NSTEP; ++t) {
        const int k0 = t * 32;
        const int dydx = k0 >> CLOG;                // wave-uniform
        const int dy = dydx / 3, dx = dydx - dy * 3;
        const int delta = (dy - 1) * W + (dx - 1);
        const int cb = ((k0 & (CI - 1)) >> 3) + lhi;
        s16x8 a[4], b[4];
#pragma unroll
        for (int mf = 0; mf < 4; ++mf)
            a[mf] = *reinterpret_cast<const s16x8*>(pa[mf] + (size_t)t * 512);
#pragma unroll
        for (int nf = 0; nf < 4; ++nf) {
            const int s = sb[nf] + delta;
            const int iy = py[nf] + dy - 1, ix = px[nf] + dx - 1;
            const bool ok = vp[nf] && (unsigned)iy < (unsigned)W && (unsigned)ix < (unsigned)W;
            const int ofs = ok ? (s * NC + (cb ^ (s & (NC - 1)))) : TOT16;
            b[nf] = *reinterpret_cast<const s16x8*>(&lds[ofs * 8]);
        }
#pragma unroll
        for (int mf = 0; mf < 4; ++mf)
#pragma unroll
            for (int nf = 0; nf < 4; ++nf)
                acc[mf][nf] = __builtin_amdgcn_mfma_f32_16x16x32_bf16(a[mf], b[nf], acc[mf][nf], 0, 0, 0);
    }

    unsigned short* outp = out + (size_t)blockIdx.z * out_stride;
#pragma unroll
    for (int mf = 0; mf < 4; ++mf) {
        const int co = blockIdx.y * CO_BLK + wm * WCO + mf * 16 + lhi * 4;
        const float b0 = bias[co], b1 = bias[co + 1], b2 = bias[co + 2], b3 = bias[co + 3];
#pragma unroll
        for (int nf = 0; nf < 4; ++nf) {
            if (!vp[nf]) continue;
            const int p = p_base + wn * WPX + nf * 16 + llo;
            f32x4 a = acc[mf][nf];
            unsigned short r[4];
            r[0] = f2bf(fmaxf(a.x + b0, 0.f));
            r[1] = f2bf(fmaxf(a.y + b1, 0.f));
            r[2] = f2bf(fmaxf(a.z + b2, 0.f));
            r[3] = f2bf(fmaxf(a.w + b3, 0.f));
            *reinterpret_cast<s16x4*>(outp + (size_t)p * CO + co) = *reinterpret_cast<s16x4*>(r);
        }
    }
}

// ======= 2x2 mean pool, NHWC bf16 =======
template<int OHW, int CO>
__global__ __launch_bounds__(256) void pool_kernel(
    const unsigned short* __restrict__ in, unsigned short* __restrict__ out,
    long in_stride, long out_stride)
{
    constexpr int W2 = OHW * 2;
    constexpr int C8 = CO / 8;
    constexpr int ITEMS = OHW * C8;
    const int n = blockIdx.x, y = blockIdx.y;
    const unsigned short* ip = in + (size_t)n * in_stride + (size_t)(2 * y) * W2 * CO;
    unsigned short* op = out + (size_t)n * out_stride + (size_t)y * OHW * CO;
    for (int it = threadIdx.x; it < ITEMS; it += 256) {
        const int x = it >> ((C8 == 16) ? 4 : 5);
        const int c0 = (it - x * C8) * 8;
        const unsigned short* q = ip + (size_t)(2 * x) * CO + c0;
        s16x8 a = *reinterpret_cast<const s16x8*>(q);
        s16x8 b = *reinterpret_cast<const s16x8*>(q + CO);
        s16x8 c = *reinterpret_cast<const s16x8*>(q + (size_t)W2 * CO);
        s16x8 d = *reinterpret_cast<const s16x8*>(q + (size_t)W2 * CO + CO);
        s16x8 r;
#pragma unroll
        for (int j = 0; j < 8; ++j)
            r[j] = (short)f2bf(0.25f * (bf2f((unsigned short)a[j]) + bf2f((unsigned short)b[j]) +
                                        bf2f((unsigned short)c[j]) + bf2f((unsigned short)d[j])));
        *reinterpret_cast<s16x8*>(op + (size_t)x * CO + c0) = r;
    }
}

// ======= global average pool over 625 pixels, NHWC bf16 -> f32 =======
__global__ __launch_bounds__(256) void gap_kernel(
    const unsigned short* __restrict__ in, float* __restrict__ gap,
    int n0, long in_stride)
{
    __shared__ float sm[4][512];
    const unsigned short* ip = in + (size_t)blockIdx.x * in_stride;
    const int g = threadIdx.x >> 6;
    const int c8 = threadIdx.x & 63;
    float s[8] = {};
    for (int p = g; p < 625; p += 4) {
        s16x8 v = *reinterpret_cast<const s16x8*>(ip + (size_t)p * 512 + c8 * 8);
#pragma unroll
        for (int j = 0; j < 8; ++j) s[j] += bf2f((unsigned short)v[j]);
    }
#pragma unroll
    for (int j = 0; j < 8; ++j) sm[g][c8 * 8 + j] = s[j];
    __syncthreads();
    if (g == 0) {
#pragma unroll
        for (int j = 0; j < 8; ++j) {
            const int ch = c8 * 8 + j;
            const float t = sm[0][ch] + sm[1][ch] + sm[2][ch] + sm[3][ch];
            gap[(size_t)(n0 + blockIdx.x) * 512 + ch] = t * (1.f / 625.f);
        }
    }
}

// ======= small fused kernels for the relation head =======
__global__ __launch_bounds__(256) void prod_kernel(
    const float* __restrict__ er, const int* __restrict__ pair, float* __restrict__ pr)
{
    const int r = blockIdx.x;
    const int p0 = pair[2 * r], p1 = pair[2 * r + 1];
    for (int i = threadIdx.x; i < 1024; i += 256) {
        const int src = (i < 512) ? p0 : p1;
        pr[(size_t)r * 1024 + i] = er[(size_t)src * 1024 + i];
    }
}

__global__ __launch_bounds__(256) void rcat_kernel(
    const float* __restrict__ prodr, const float* __restrict__ ef, float* __restrict__ rc)
{
    const int r = blockIdx.x;
    for (int i = threadIdx.x; i < 1536; i += 256) {
        float v;
        if (i < 512)       v = prodr[(size_t)r * 1024 + i];
        else if (i < 1024) v = ef[(size_t)r * 512 + (i - 512)];
        else               v = prodr[(size_t)r * 1024 + (i - 1024) + 512];
        rc[(size_t)r * 1536 + i] = v;
    }
}

__global__ __launch_bounds__(256) void cat8_kernel(
    const float* __restrict__ pwe, const float* __restrict__ un, float* __restrict__ cat)
{
    const int r = blockIdx.x;
    for (int i = threadIdx.x; i < 8192; i += 256) {
        cat[(size_t)r * 8192 + i] = (i < 4096) ? pwe[(size_t)r * 4096 + i]
                                               : un[(size_t)r * 4096 + (i - 4096)];
    }
}

__global__ __launch_bounds__(256) void reldist_kernel(
    const float* __restrict__ rf, const float* __restrict__ Wr, const float* __restrict__ br,
    const float* __restrict__ freq, const int* __restrict__ preds,
    const int* __restrict__ pair, float* __restrict__ out)
{
    const int idx = blockIdx.x * 256 + threadIdx.x;
    if (idx >= 128 * 51) return;
    const int r = idx / 51, j = idx - r * 51;
    const float* a = rf + (size_t)r * 512;
    float s = br[j];
    for (int k = 0; k < 512; ++k) s += a[k] * Wr[(size_t)k * 51 + j];
    const int c0 = preds[pair[2 * r]], c1 = preds[pair[2 * r + 1]];
    s += freq[((size_t)c0 * 151 + c1) * 51 + j];
    out[idx] = s;
}

// ===========================================================================
extern "C" void kernel_launch(void* const* d_in, const int* in_sizes, int n_in,
                              void* d_out, int out_size, void* d_ws, size_t ws_size,
                              hipStream_t stream)
{
    const float* obj_feats  = (const float*)d_in[0];
    const int*   obj_preds  = (const int*)  d_in[1];
    const int*   pair       = (const int*)  d_in[2];
    const float* unionf     = (const float*)d_in[3];
    const float* W_post_emb = (const float*)d_in[4];
    const float* b_post_emb = (const float*)d_in[5];
    const float* W_post_cat = (const float*)d_in[6];
    const float* b_post_cat = (const float*)d_in[7];
    const float* W_edge     = (const float*)d_in[8];
    const float* b_edge     = (const float*)d_in[9];
    const float* W_lin      = (const float*)d_in[10];
    const float* b_lin      = (const float*)d_in[11];
    const float* W_rel      = (const float*)d_in[12];
    const float* b_rel      = (const float*)d_in[13];
    const float* freq       = (const float*)d_in[14];
    const float* emb        = (const float*)d_in[15];
    const float* cw1 = (const float*)d_in[16]; const float* cb1 = (const float*)d_in[17];
    const float* cw2 = (const float*)d_in[18]; const float* cb2 = (const float*)d_in[19];
    const float* cw3 = (const float*)d_in[20]; const float* cb3 = (const float*)d_in[21];
    const float* cw4 = (const float*)d_in[22]; const float* cb4 = (const float*)d_in[23];
    const float* cw5 = (const float*)d_in[24]; const float* cb5 = (const float*)d_in[25];
    const float* cw6 = (const float*)d_in[26]; const float* cb6 = (const float*)d_in[27];
    const float* Ww1 = (const float*)d_in[28]; const float* bw1 = (const float*)d_in[29];
    const float* Ww2 = (const float*)d_in[30]; const float* bw2 = (const float*)d_in[31];
    float* out = (float*)d_out;

    // ---- workspace layout (floats) ----
    float* ws = (float*)d_ws;
    float* edge_rep   = ws;                       // 1024*1024
    float* prodr      = edge_rep + 1048576;       // 128*1024
    float* visual     = prodr + 131072;           // 128*4096
    float* edge_feats = visual + 524288;          // 128*512
    float* rcat       = edge_feats + 65536;       // 128*1536
    float* rel_feats  = rcat + 196608;            // 128*512
    float* gap        = rel_feats + 65536;        // 128*512
    float* x5         = gap + 65536;              // 128*384
    float* pwe        = x5 + 49152;               // 128*4096
    float* cat8       = pwe + 524288;             // 128*8192
    float* hbuf       = cat8 + 1048576;           // 128*512
    float* part       = hbuf + 65536;             // 2097152 (split-K partials)
    const size_t persist_f32 = 3784704ull + 2097152ull;

    unsigned short* wsu = (unsigned short*)(ws + persist_f32);
    unsigned short* w2r = wsu;                    // 128*576
    unsigned short* w3r = w2r + 73728;            // 256*1152
    unsigned short* w4r = w3r + 294912;           // 512*2304
    unsigned short* actA = w4r + 1179648;

    int C = 128;
    const size_t base_bytes = persist_f32 * 4 + 1548288ull * 2;
    while (C > 1 && base_bytes + (size_t)C * 1920000ull * 2 > ws_size) C >>= 1;
    unsigned short* actB = actA + (size_t)C * 640000;

    // ---- relation branch ----
    gemm_kernel<false,false,false><<<dim3(16,16),256,0,stream>>>(obj_feats, W_post_emb, b_post_emb, nullptr, edge_rep, 1024,1024,512);
    prod_kernel<<<dim3(128),256,0,stream>>>(edge_rep, pair, prodr);
    gemmsk_kernel<false><<<dim3(2,64,4),256,0,stream>>>(prodr, W_post_cat, part, 128,4096,1024, 256);
    reduce_kernel<false,true ><<<dim3(2048),256,0,stream>>>(part, b_post_cat, unionf, visual, 128,4096,4);
    gemmsk_kernel<false><<<dim3(2,8,16),256,0,stream>>>(visual, W_edge, part, 128,512,4096, 256);
    reduce_kernel<true ,false><<<dim3(256),256,0,stream>>>(part, b_edge, nullptr, edge_feats, 128,512,16);
    rcat_kernel<<<dim3(128),256,0,stream>>>(prodr, edge_feats, rcat);
    gemmsk_kernel<false><<<dim3(2,8,8),256,0,stream>>>(rcat, W_lin, part, 128,512,1536, 192);
    reduce_kernel<false,false><<<dim3(256),256,0,stream>>>(part, b_lin, nullptr, rel_feats, 128,512,8);
    reldist_kernel<<<dim3(26),256,0,stream>>>(rel_feats, W_rel, b_rel, freq, obj_preds, pair, out);

    // ---- weight repacks (bf16, MFMA-fragment-contiguous) ----
    frepack_kernel<<<dim3(36), 256,0,stream>>>(cw2, w2r, 128, 64, 18, 6);
    frepack_kernel<<<dim3(144),256,0,stream>>>(cw3, w3r, 256, 128, 36, 7);
    frepack_kernel<<<dim3(576),256,0,stream>>>(cw4, w4r, 512, 256, 72, 8);

    // ---- conv chain (LDS-staged MFMA implicit GEMM, NHWC bf16) ----
    for (int n0 = 0; n0 < 128; n0 += C) {
        conv1_kernel<<<dim3(C,8),256,0,stream>>>(emb, pair, cw1, cb1, actA, n0, 640000);
        convlds_kernel<64,100,128,128,2,2><<<dim3(79,1,C),256,0,stream>>>(actA, w2r, cb2, actB, 128, 640000, 1280000);
        pool_kernel<50,128><<<dim3(C,50),256,0,stream>>>(actB, actA, 1280000, 640000);
        convlds_kernel<128,50,128,128,2,2><<<dim3(20,2,C),256,0,stream>>>(actA, w3r, cb3, actB, 256, 640000, 1280000);
        pool_kernel<25,256><<<dim3(C,25),256,0,stream>>>(actB, actA, 1280000, 640000);
        convlds_kernel<256,25,256,64,4,1><<<dim3(10,2,C),256,0,stream>>>(actA, w4r, cb4, actB, 512, 640000, 1280000);
        gap_kernel<<<dim3(C),256,0,stream>>>(actB, gap, n0, 1280000);
    }

    // ---- conv tail (1x1 convs as GEMMs, B^T layout) ----
    gemmsk_kernel<true ><<<dim3(2,6,8),256,0,stream>>>(gap, cw5, part, 128,384,512, 64);
    reduce_kernel<true ,false><<<dim3(192),256,0,stream>>>(part, cb5, nullptr, x5, 128,384,8);
    gemmsk_kernel<true ><<<dim3(2,64,4),256,0,stream>>>(x5, cw6, part, 128,4096,384, 96);
    reduce_kernel<false,false><<<dim3(2048),256,0,stream>>>(part, cb6, nullptr, pwe, 128,4096,4);

    // ---- union head ----
    cat8_kernel<<<dim3(128),256,0,stream>>>(pwe, unionf, cat8);
    gemmsk_kernel<false><<<dim3(2,8,32),256,0,stream>>>(cat8, Ww1, part, 128,512,8192, 256);
    reduce_kernel<true ,false><<<dim3(256),256,0,stream>>>(part, bw1, nullptr, hbuf, 128,512,32);
    gemmsk_kernel<false><<<dim3(2,64,4),256,0,stream>>>(hbuf, Ww2, part, 128,4096,512, 128);
    reduce_kernel<true ,false><<<dim3(2048),256,0,stream>>>(part, bw2, nullptr, out + 6528, 128,4096,4);
}

// Round 6
// 1563.822 us; speedup vs baseline: 6.5627x; 1.0790x over previous
//
#include <hip/hip_runtime.h>
#include <hip/hip_bf16.h>

// ---------------------------------------------------------------------------
// HID=512 POOL=4096 N_OBJ_CLS=151 N_REL_CLS=51 EMB=200 N_OBJ=1024 N_REL=128
// ---------------------------------------------------------------------------

typedef __attribute__((ext_vector_type(8))) short  s16x8;
typedef __attribute__((ext_vector_type(4))) short  s16x4;
typedef __attribute__((ext_vector_type(4))) float  f32x4;

__device__ inline unsigned short f2bf(float f) {
    unsigned u = __builtin_bit_cast(unsigned, f);
    u = (u + 0x7FFF + ((u >> 16) & 1)) >> 16;
    return (unsigned short)u;
}
__device__ inline float bf2f(unsigned short s) {
    unsigned u = ((unsigned)s) << 16;
    return __builtin_bit_cast(float, u);
}

// ======================= generic f32 GEMM (64x64 tile) ======================
template<bool BT, bool RELU, bool MUL>
__global__ __launch_bounds__(256) void gemm_kernel(
    const float* __restrict__ A, const float* __restrict__ B,
    const float* __restrict__ bias, const float* __restrict__ mulp,
    float* __restrict__ C, int M, int N, int K)
{
    __shared__ float As[16][68];
    __shared__ float Bs[16][68];
    const int m0 = blockIdx.x * 64, n0 = blockIdx.y * 64;
    const int tid = threadIdx.x;
    const int ty = tid >> 4, tx = tid & 15;
    float acc[4][4] = {};
    for (int k0 = 0; k0 < K; k0 += 16) {
        {
            const int m = tid >> 2, kq = (tid & 3) << 2;
            const float4 a = *reinterpret_cast<const float4*>(A + (size_t)(m0 + m) * K + k0 + kq);
            As[kq + 0][m] = a.x; As[kq + 1][m] = a.y; As[kq + 2][m] = a.z; As[kq + 3][m] = a.w;
        }
        if (!BT) {
            const int kk = tid >> 4, nq = (tid & 15) << 2;
            const float4 b = *reinterpret_cast<const float4*>(B + (size_t)(k0 + kk) * N + n0 + nq);
            *reinterpret_cast<float4*>(&Bs[kk][nq]) = b;
        } else {
            const int nn = tid >> 2, kq = (tid & 3) << 2;
            const float4 b = *reinterpret_cast<const float4*>(B + (size_t)(n0 + nn) * K + k0 + kq);
            Bs[kq + 0][nn] = b.x; Bs[kq + 1][nn] = b.y; Bs[kq + 2][nn] = b.z; Bs[kq + 3][nn] = b.w;
        }
        __syncthreads();
#pragma unroll
        for (int k = 0; k < 16; ++k) {
            const float4 av = *reinterpret_cast<const float4*>(&As[k][ty << 2]);
            const float4 bv = *reinterpret_cast<const float4*>(&Bs[k][tx << 2]);
            acc[0][0] += av.x * bv.x; acc[0][1] += av.x * bv.y; acc[0][2] += av.x * bv.z; acc[0][3] += av.x * bv.w;
            acc[1][0] += av.y * bv.x; acc[1][1] += av.y * bv.y; acc[1][2] += av.y * bv.z; acc[1][3] += av.y * bv.w;
            acc[2][0] += av.z * bv.x; acc[2][1] += av.z * bv.y; acc[2][2] += av.z * bv.z; acc[2][3] += av.z * bv.w;
            acc[3][0] += av.w * bv.x; acc[3][1] += av.w * bv.y; acc[3][2] += av.w * bv.z; acc[3][3] += av.w * bv.w;
        }
        __syncthreads();
    }
#pragma unroll
    for (int i = 0; i < 4; ++i) {
        const int m = m0 + (ty << 2) + i;
#pragma unroll
        for (int j = 0; j < 4; ++j) {
            const int n = n0 + (tx << 2) + j;
            float v = acc[i][j] + bias[n];
            if (MUL) v *= mulp[(size_t)m * N + n];
            if (RELU) v = fmaxf(v, 0.f);
            C[(size_t)m * N + n] = v;
        }
    }
}

// =================== split-K f32 GEMM: partials + reduce ====================
template<bool BT>
__global__ __launch_bounds__(256) void gemmsk_kernel(
    const float* __restrict__ A, const float* __restrict__ B,
    float* __restrict__ part, int M, int N, int K, int kchunk)
{
    __shared__ float As[16][68];
    __shared__ float Bs[16][68];
    const int m0 = blockIdx.x * 64, n0 = blockIdx.y * 64;
    const int kbeg = blockIdx.z * kchunk, kend = kbeg + kchunk;
    const int tid = threadIdx.x;
    const int ty = tid >> 4, tx = tid & 15;
    float acc[4][4] = {};
    for (int k0 = kbeg; k0 < kend; k0 += 16) {
        {
            const int m = tid >> 2, kq = (tid & 3) << 2;
            const float4 a = *reinterpret_cast<const float4*>(A + (size_t)(m0 + m) * K + k0 + kq);
            As[kq + 0][m] = a.x; As[kq + 1][m] = a.y; As[kq + 2][m] = a.z; As[kq + 3][m] = a.w;
        }
        if (!BT) {
            const int kk = tid >> 4, nq = (tid & 15) << 2;
            const float4 b = *reinterpret_cast<const float4*>(B + (size_t)(k0 + kk) * N + n0 + nq);
            *reinterpret_cast<float4*>(&Bs[kk][nq]) = b;
        } else {
            const int nn = tid >> 2, kq = (tid & 3) << 2;
            const float4 b = *reinterpret_cast<const float4*>(B + (size_t)(n0 + nn) * K + k0 + kq);
            Bs[kq + 0][nn] = b.x; Bs[kq + 1][nn] = b.y; Bs[kq + 2][nn] = b.z; Bs[kq + 3][nn] = b.w;
        }
        __syncthreads();
#pragma unroll
        for (int k = 0; k < 16; ++k) {
            const float4 av = *reinterpret_cast<const float4*>(&As[k][ty << 2]);
            const float4 bv = *reinterpret_cast<const float4*>(&Bs[k][tx << 2]);
            acc[0][0] += av.x * bv.x; acc[0][1] += av.x * bv.y; acc[0][2] += av.x * bv.z; acc[0][3] += av.x * bv.w;
            acc[1][0] += av.y * bv.x; acc[1][1] += av.y * bv.y; acc[1][2] += av.y * bv.z; acc[1][3] += av.y * bv.w;
            acc[2][0] += av.z * bv.x; acc[2][1] += av.z * bv.y; acc[2][2] += av.z * bv.z; acc[2][3] += av.z * bv.w;
            acc[3][0] += av.w * bv.x; acc[3][1] += av.w * bv.y; acc[3][2] += av.w * bv.z; acc[3][3] += av.w * bv.w;
        }
        __syncthreads();
    }
    float* pp = part + (size_t)blockIdx.z * M * N;
#pragma unroll
    for (int i = 0; i < 4; ++i) {
        const int m = m0 + (ty << 2) + i;
#pragma unroll
        for (int j = 0; j < 4; ++j)
            pp[(size_t)m * N + n0 + (tx << 2) + j] = acc[i][j];
    }
}

template<bool RELU, bool MUL>
__global__ __launch_bounds__(256) void reduce_kernel(
    const float* __restrict__ part, const float* __restrict__ bias,
    const float* __restrict__ mulp, float* __restrict__ C, int M, int N, int KS)
{
    const int idx = blockIdx.x * 256 + threadIdx.x;
    if (idx >= M * N) return;
    const int n = idx % N;
    float s = bias[n];
    for (int ks = 0; ks < KS; ++ks) s += part[(size_t)ks * M * N + idx];
    if (MUL) s *= mulp[idx];
    if (RELU) s = fmaxf(s, 0.f);
    C[idx] = s;
}

// ======================= conv1: separable 5x5 via rank-1 input ==============
__global__ __launch_bounds__(256) void conv1_kernel(
    const float* __restrict__ emb, const int* __restrict__ pair,
    const float* __restrict__ wgt, const float* __restrict__ bias,
    unsigned short* __restrict__ out, int n0, long out_stride)
{
    __shared__ float soe[200], sse[200];
    __shared__ float r[8][5][204];
    const int n = blockIdx.x, gn = n0 + n;
    const int co0 = blockIdx.y * 8;
    const int tid = threadIdx.x;
    const float* oe = emb + (size_t)(pair[2 * gn + 0] + 1) * 200;
    const float* se = emb + (size_t)(pair[2 * gn + 1] + 1) * 200;
    if (tid < 200) { soe[tid] = oe[tid]; sse[tid] = se[tid]; }
    __syncthreads();
    for (int it = tid; it < 8000; it += 256) {
        const int c = it / 1000;
        const int rem = it - c * 1000;
        const int dy = rem / 200;
        const int j = rem - dy * 200;
        const float* w = wgt + (size_t)(co0 + c) * 25 + dy * 5;
        float s = 0.f;
#pragma unroll
        for (int dx = 0; dx < 5; ++dx) {
            const int jj = j + dx - 2;
            if ((unsigned)jj < 200u) s += w[dx] * sse[jj];
        }
        r[c][dy][j] = s;
    }
    __syncthreads();
    float bz[8];
#pragma unroll
    for (int c = 0; c < 8; ++c) bz[c] = bias[co0 + c];
    for (int p = tid; p < 10000; p += 256) {
        const int py = p / 100, px = p - py * 100;
        const int i0 = 2 * py - 2, j0 = 2 * px;
        float ov[6];
#pragma unroll
        for (int t = 0; t < 6; ++t) {
            const int ii = i0 + t;
            ov[t] = ((unsigned)ii < 200u) ? soe[ii] : 0.f;
        }
        unsigned short vals[8];
#pragma unroll
        for (int c = 0; c < 8; ++c) {
            float s00 = bz[c], s01 = bz[c], s10 = bz[c], s11 = bz[c];
#pragma unroll
            for (int dy = 0; dy < 5; ++dy) {
                const float2 rv = *reinterpret_cast<const float2*>(&r[c][dy][j0]);
                s00 += ov[dy]     * rv.x; s01 += ov[dy]     * rv.y;
                s10 += ov[dy + 1] * rv.x; s11 += ov[dy + 1] * rv.y;
            }
            vals[c] = f2bf(0.25f * (fmaxf(s00, 0.f) + fmaxf(s01, 0.f) +
                                    fmaxf(s10, 0.f) + fmaxf(s11, 0.f)));
        }
        *reinterpret_cast<s16x8*>(out + (size_t)n * out_stride + (size_t)p * 64 + co0) =
            *reinterpret_cast<s16x8*>(vals);
    }
}

// ======= weight repack: OIHW f32 -> MFMA A-fragment-contiguous bf16 =======
// layout: [g = co/16][t = k-step][lane][8]  where lane&15 = co%16,
// kk = t*32 + (lane>>4)*8 + e, ci = kk & (CI-1), dydx = kk >> CLOG.
__global__ __launch_bounds__(256) void frepack_kernel(
    const float* __restrict__ w, unsigned short* __restrict__ o,
    int CO, int CI, int NSTEP, int CLOG)
{
    const int id = blockIdx.x * 256 + threadIdx.x;
    const int total = (CO >> 4) * NSTEP * 64;
    if (id >= total) return;
    const int lane = id & 63;
    const int gt = id >> 6;
    const int t = gt % NSTEP, g = gt / NSTEP;
    const int co = g * 16 + (lane & 15);
    unsigned short r[8];
#pragma unroll
    for (int e = 0; e < 8; ++e) {
        const int kk = t * 32 + ((lane >> 4) << 3) + e;
        const int ci = kk & (CI - 1);
        const int dydx = kk >> CLOG;
        const int dy = dydx / 3, dx = dydx - dy * 3;
        r[e] = f2bf(w[((size_t)(co * CI + ci) * 3 + dy) * 3 + dx]);
    }
    *reinterpret_cast<s16x8*>(o + (size_t)id * 8) = *reinterpret_cast<s16x8*>(r);
}

// ======= LDS-staged implicit-GEMM MFMA 3x3 conv, pad=1, relu, NHWC bf16 =====
// Block: CO_BLK co x PX_BLK px, 4 waves (WM x WN), wave tile MF*16 co x NF*16 px.
// Input strip staged in LDS (XOR-swizzled), K-loop barrier-free; weights read
// as contiguous pre-packed fragments.
template<int CI, int W, int CO_BLK, int PX_BLK, int WM, int WN, int MF, int NF>
__global__ __launch_bounds__(256) void convlds_kernel(
    const unsigned short* __restrict__ in, const unsigned short* __restrict__ wf,
    const float* __restrict__ bias, unsigned short* __restrict__ out,
    int CO, long in_stride, long out_stride)
{
    constexpr int NPIX = W * W;
    constexpr int K = 9 * CI;
    constexpr int NSTEP = K / 32;
    constexpr int NC = CI / 8;                      // 16B chunks per pixel
    constexpr int NCL = (NC == 8) ? 3 : (NC == 16) ? 4 : 5;
    constexpr int CLOG = (CI == 64) ? 6 : (CI == 128) ? 7 : 8;
    constexpr int STAGE_PX = PX_BLK + 2 * W + 2;
    constexpr int TOT16 = STAGE_PX * NC;
    constexpr int WCO = CO_BLK / WM;                // = MF*16
    constexpr int WPX = PX_BLK / WN;                // = NF*16
    __shared__ unsigned short lds[STAGE_PX * CI + 8];

    const int tid = threadIdx.x;
    const unsigned short* inp = in + (size_t)blockIdx.z * in_stride;
    const int p_base = blockIdx.x * PX_BLK;
    const int q0 = p_base - (W + 1);

    // ---- stage input strip (clamped; borders handled by read predication) ----
    for (int i = tid; i < TOT16; i += 256) {
        const int s = i >> NCL;
        const int c = i & (NC - 1);
        int q = q0 + s;
        q = q < 0 ? 0 : (q >= NPIX ? NPIX - 1 : q);
        s16x8 v = *reinterpret_cast<const s16x8*>(inp + (size_t)q * CI + c * 8);
        const int perm = c ^ (s & (NC - 1));
        *reinterpret_cast<s16x8*>(&lds[(s * NC + perm) * 8]) = v;
    }
    if (tid == 0) *reinterpret_cast<s16x8*>(&lds[STAGE_PX * CI]) = s16x8{};
    __syncthreads();

    const int lane = tid & 63, wid = tid >> 6;
    const int wm = wid % WM, wn = wid / WM;
    const int lhi = lane >> 4, llo = lane & 15;
    const int g0 = (blockIdx.y * CO_BLK + wm * WCO) >> 4;

    const unsigned short* pa[MF];
#pragma unroll
    for (int mf = 0; mf < MF; ++mf)
        pa[mf] = wf + ((size_t)(g0 + mf) * NSTEP * 64 + lane) * 8;

    int sb[NF], py[NF], px[NF];
    bool vp[NF];
#pragma unroll
    for (int nf = 0; nf < NF; ++nf) {
        const int p = p_base + wn * WPX + nf * 16 + llo;
        vp[nf] = p < NPIX;
        py[nf] = p / W; px[nf] = p - py[nf] * W;
        sb[nf] = p - q0;
    }

    f32x4 acc[MF][NF] = {};
#pragma unroll 2
    for (int t = 0; t < NSTEP; ++t) {
        const int k0 = t * 32;
        const int dydx = k0 >> CLOG;                // wave-uniform
        const int dy = dydx / 3, dx = dydx - dy * 3;
        const int delta = (dy - 1) * W + (dx - 1);
        const int cb = ((k0 & (CI - 1)) >> 3) + lhi;
        s16x8 a[MF], b[NF];
#pragma unroll
        for (int mf = 0; mf < MF; ++mf)
            a[mf] = *reinterpret_cast<const s16x8*>(pa[mf] + (size_t)t * 512);
#pragma unroll
        for (int nf = 0; nf < NF; ++nf) {
            const int s = sb[nf] + delta;
            const int iy = py[nf] + dy - 1, ix = px[nf] + dx - 1;
            const bool ok = vp[nf] && (unsigned)iy < (unsigned)W && (unsigned)ix < (unsigned)W;
            const int ofs = ok ? (s * NC + (cb ^ (s & (NC - 1)))) : TOT16;
            b[nf] = *reinterpret_cast<const s16x8*>(&lds[ofs * 8]);
        }
#pragma unroll
        for (int mf = 0; mf < MF; ++mf)
#pragma unroll
            for (int nf = 0; nf < NF; ++nf)
                acc[mf][nf] = __builtin_amdgcn_mfma_f32_16x16x32_bf16(a[mf], b[nf], acc[mf][nf], 0, 0, 0);
    }

    unsigned short* outp = out + (size_t)blockIdx.z * out_stride;
#pragma unroll
    for (int mf = 0; mf < MF; ++mf) {
        const int co = blockIdx.y * CO_BLK + wm * WCO + mf * 16 + lhi * 4;
        const float b0 = bias[co], b1 = bias[co + 1], b2 = bias[co + 2], b3 = bias[co + 3];
#pragma unroll
        for (int nf = 0; nf < NF; ++nf) {
            if (!vp[nf]) continue;
            const int p = p_base + wn * WPX + nf * 16 + llo;
            f32x4 a = acc[mf][nf];
            unsigned short r[4];
            r[0] = f2bf(fmaxf(a.x + b0, 0.f));
            r[1] = f2bf(fmaxf(a.y + b1, 0.f));
            r[2] = f2bf(fmaxf(a.z + b2, 0.f));
            r[3] = f2bf(fmaxf(a.w + b3, 0.f));
            *reinterpret_cast<s16x4*>(outp + (size_t)p * CO + co) = *reinterpret_cast<s16x4*>(r);
        }
    }
}

// ======= 2x2 mean pool, NHWC bf16 =======
template<int OHW, int CO>
__global__ __launch_bounds__(256) void pool_kernel(
    const unsigned short* __restrict__ in, unsigned short* __restrict__ out,
    long in_stride, long out_stride)
{
    constexpr int W2 = OHW * 2;
    constexpr int C8 = CO / 8;
    constexpr int ITEMS = OHW * C8;
    const int n = blockIdx.x, y = blockIdx.y;
    const unsigned short* ip = in + (size_t)n * in_stride + (size_t)(2 * y) * W2 * CO;
    unsigned short* op = out + (size_t)n * out_stride + (size_t)y * OHW * CO;
    for (int it = threadIdx.x; it < ITEMS; it += 256) {
        const int x = it >> ((C8 == 16) ? 4 : 5);
        const int c0 = (it - x * C8) * 8;
        const unsigned short* q = ip + (size_t)(2 * x) * CO + c0;
        s16x8 a = *reinterpret_cast<const s16x8*>(q);
        s16x8 b = *reinterpret_cast<const s16x8*>(q + CO);
        s16x8 c = *reinterpret_cast<const s16x8*>(q + (size_t)W2 * CO);
        s16x8 d = *reinterpret_cast<const s16x8*>(q + (size_t)W2 * CO + CO);
        s16x8 r;
#pragma unroll
        for (int j = 0; j < 8; ++j)
            r[j] = (short)f2bf(0.25f * (bf2f((unsigned short)a[j]) + bf2f((unsigned short)b[j]) +
                                        bf2f((unsigned short)c[j]) + bf2f((unsigned short)d[j])));
        *reinterpret_cast<s16x8*>(op + (size_t)x * CO + c0) = r;
    }
}

// ======= global average pool over 625 pixels, NHWC bf16 -> f32 =======
__global__ __launch_bounds__(256) void gap_kernel(
    const unsigned short* __restrict__ in, float* __restrict__ gap,
    int n0, long in_stride)
{
    __shared__ float sm[4][512];
    const unsigned short* ip = in + (size_t)blockIdx.x * in_stride;
    const int g = threadIdx.x >> 6;
    const int c8 = threadIdx.x & 63;
    float s[8] = {};
    for (int p = g; p < 625; p += 4) {
        s16x8 v = *reinterpret_cast<const s16x8*>(ip + (size_t)p * 512 + c8 * 8);
#pragma unroll
        for (int j = 0; j < 8; ++j) s[j] += bf2f((unsigned short)v[j]);
    }
#pragma unroll
    for (int j = 0; j < 8; ++j) sm[g][c8 * 8 + j] = s[j];
    __syncthreads();
    if (g == 0) {
#pragma unroll
        for (int j = 0; j < 8; ++j) {
            const int ch = c8 * 8 + j;
            const float t = sm[0][ch] + sm[1][ch] + sm[2][ch] + sm[3][ch];
            gap[(size_t)(n0 + blockIdx.x) * 512 + ch] = t * (1.f / 625.f);
        }
    }
}

// ======= small fused kernels for the relation head =======
__global__ __launch_bounds__(256) void prod_kernel(
    const float* __restrict__ er, const int* __restrict__ pair, float* __restrict__ pr)
{
    const int r = blockIdx.x;
    const int p0 = pair[2 * r], p1 = pair[2 * r + 1];
    for (int i = threadIdx.x; i < 1024; i += 256) {
        const int src = (i < 512) ? p0 : p1;
        pr[(size_t)r * 1024 + i] = er[(size_t)src * 1024 + i];
    }
}

__global__ __launch_bounds__(256) void rcat_kernel(
    const float* __restrict__ prodr, const float* __restrict__ ef, float* __restrict__ rc)
{
    const int r = blockIdx.x;
    for (int i = threadIdx.x; i < 1536; i += 256) {
        float v;
        if (i < 512)       v = prodr[(size_t)r * 1024 + i];
        else if (i < 1024) v = ef[(size_t)r * 512 + (i - 512)];
        else               v = prodr[(size_t)r * 1024 + (i - 1024) + 512];
        rc[(size_t)r * 1536 + i] = v;
    }
}

__global__ __launch_bounds__(256) void cat8_kernel(
    const float* __restrict__ pwe, const float* __restrict__ un, float* __restrict__ cat)
{
    const int r = blockIdx.x;
    for (int i = threadIdx.x; i < 8192; i += 256) {
        cat[(size_t)r * 8192 + i] = (i < 4096) ? pwe[(size_t)r * 4096 + i]
                                               : un[(size_t)r * 4096 + (i - 4096)];
    }
}

__global__ __launch_bounds__(256) void reldist_kernel(
    const float* __restrict__ rf, const float* __restrict__ Wr, const float* __restrict__ br,
    const float* __restrict__ freq, const int* __restrict__ preds,
    const int* __restrict__ pair, float* __restrict__ out)
{
    const int idx = blockIdx.x * 256 + threadIdx.x;
    if (idx >= 128 * 51) return;
    const int r = idx / 51, j = idx - r * 51;
    const float* a = rf + (size_t)r * 512;
    float s = br[j];
    for (int k = 0; k < 512; ++k) s += a[k] * Wr[(size_t)k * 51 + j];
    const int c0 = preds[pair[2 * r]], c1 = preds[pair[2 * r + 1]];
    s += freq[((size_t)c0 * 151 + c1) * 51 + j];
    out[idx] = s;
}

// ===========================================================================
extern "C" void kernel_launch(void* const* d_in, const int* in_sizes, int n_in,
                              void* d_out, int out_size, void* d_ws, size_t ws_size,
                              hipStream_t stream)
{
    const float* obj_feats  = (const float*)d_in[0];
    const int*   obj_preds  = (const int*)  d_in[1];
    const int*   pair       = (const int*)  d_in[2];
    const float* unionf     = (const float*)d_in[3];
    const float* W_post_emb = (const float*)d_in[4];
    const float* b_post_emb = (const float*)d_in[5];
    const float* W_post_cat = (const float*)d_in[6];
    const float* b_post_cat = (const float*)d_in[7];
    const float* W_edge     = (const float*)d_in[8];
    const float* b_edge     = (const float*)d_in[9];
    const float* W_lin      = (const float*)d_in[10];
    const float* b_lin      = (const float*)d_in[11];
    const float* W_rel      = (const float*)d_in[12];
    const float* b_rel      = (const float*)d_in[13];
    const float* freq       = (const float*)d_in[14];
    const float* emb        = (const float*)d_in[15];
    const float* cw1 = (const float*)d_in[16]; const float* cb1 = (const float*)d_in[17];
    const float* cw2 = (const float*)d_in[18]; const float* cb2 = (const float*)d_in[19];
    const float* cw3 = (const float*)d_in[20]; const float* cb3 = (const float*)d_in[21];
    const float* cw4 = (const float*)d_in[22]; const float* cb4 = (const float*)d_in[23];
    const float* cw5 = (const float*)d_in[24]; const float* cb5 = (const float*)d_in[25];
    const float* cw6 = (const float*)d_in[26]; const float* cb6 = (const float*)d_in[27];
    const float* Ww1 = (const float*)d_in[28]; const float* bw1 = (const float*)d_in[29];
    const float* Ww2 = (const float*)d_in[30]; const float* bw2 = (const float*)d_in[31];
    float* out = (float*)d_out;

    // ---- workspace layout (floats) ----
    float* ws = (float*)d_ws;
    float* edge_rep   = ws;                       // 1024*1024
    float* prodr      = edge_rep + 1048576;       // 128*1024
    float* visual     = prodr + 131072;           // 128*4096
    float* edge_feats = visual + 524288;          // 128*512
    float* rcat       = edge_feats + 65536;       // 128*1536
    float* rel_feats  = rcat + 196608;            // 128*512
    float* gap        = rel_feats + 65536;        // 128*512
    float* x5         = gap + 65536;              // 128*384
    float* pwe        = x5 + 49152;               // 128*4096
    float* cat8       = pwe + 524288;             // 128*8192
    float* hbuf       = cat8 + 1048576;           // 128*512
    float* part       = hbuf + 65536;             // 2097152 (split-K partials)
    const size_t persist_f32 = 3784704ull + 2097152ull;

    unsigned short* wsu = (unsigned short*)(ws + persist_f32);
    unsigned short* w2r = wsu;                    // 128*576
    unsigned short* w3r = w2r + 73728;            // 256*1152
    unsigned short* w4r = w3r + 294912;           // 512*2304
    unsigned short* actA = w4r + 1179648;

    int C = 128;
    const size_t base_bytes = persist_f32 * 4 + 1548288ull * 2;
    while (C > 1 && base_bytes + (size_t)C * 1920000ull * 2 > ws_size) C >>= 1;
    unsigned short* actB = actA + (size_t)C * 640000;

    // ---- relation branch ----
    gemm_kernel<false,false,false><<<dim3(16,16),256,0,stream>>>(obj_feats, W_post_emb, b_post_emb, nullptr, edge_rep, 1024,1024,512);
    prod_kernel<<<dim3(128),256,0,stream>>>(edge_rep, pair, prodr);
    gemmsk_kernel<false><<<dim3(2,64,4),256,0,stream>>>(prodr, W_post_cat, part, 128,4096,1024, 256);
    reduce_kernel<false,true ><<<dim3(2048),256,0,stream>>>(part, b_post_cat, unionf, visual, 128,4096,4);
    gemmsk_kernel<false><<<dim3(2,8,16),256,0,stream>>>(visual, W_edge, part, 128,512,4096, 256);
    reduce_kernel<true ,false><<<dim3(256),256,0,stream>>>(part, b_edge, nullptr, edge_feats, 128,512,16);
    rcat_kernel<<<dim3(128),256,0,stream>>>(prodr, edge_feats, rcat);
    gemmsk_kernel<false><<<dim3(2,8,8),256,0,stream>>>(rcat, W_lin, part, 128,512,1536, 192);
    reduce_kernel<false,false><<<dim3(256),256,0,stream>>>(part, b_lin, nullptr, rel_feats, 128,512,8);
    reldist_kernel<<<dim3(26),256,0,stream>>>(rel_feats, W_rel, b_rel, freq, obj_preds, pair, out);

    // ---- weight repacks (bf16, MFMA-fragment-contiguous) ----
    frepack_kernel<<<dim3(36), 256,0,stream>>>(cw2, w2r, 128, 64, 18, 6);
    frepack_kernel<<<dim3(144),256,0,stream>>>(cw3, w3r, 256, 128, 36, 7);
    frepack_kernel<<<dim3(576),256,0,stream>>>(cw4, w4r, 512, 256, 72, 8);

    // ---- conv chain (LDS-staged MFMA implicit GEMM, NHWC bf16) ----
    for (int n0 = 0; n0 < 128; n0 += C) {
        conv1_kernel<<<dim3(C,8),256,0,stream>>>(emb, pair, cw1, cb1, actA, n0, 640000);
        convlds_kernel<64,100,128,128,2,2,4,4><<<dim3(79,1,C),256,0,stream>>>(actA, w2r, cb2, actB, 128, 640000, 1280000);
        pool_kernel<50,128><<<dim3(C,50),256,0,stream>>>(actB, actA, 1280000, 640000);
        convlds_kernel<128,50,256,64,4,1,4,4><<<dim3(40,1,C),256,0,stream>>>(actA, w3r, cb3, actB, 256, 640000, 1280000);
        pool_kernel<25,256><<<dim3(C,25),256,0,stream>>>(actB, actA, 1280000, 640000);
        convlds_kernel<256,25,512,32,4,1,8,2><<<dim3(20,1,C),256,0,stream>>>(actA, w4r, cb4, actB, 512, 640000, 1280000);
        gap_kernel<<<dim3(C),256,0,stream>>>(actB, gap, n0, 1280000);
    }

    // ---- conv tail (1x1 convs as GEMMs, B^T layout) ----
    gemmsk_kernel<true ><<<dim3(2,6,8),256,0,stream>>>(gap, cw5, part, 128,384,512, 64);
    reduce_kernel<true ,false><<<dim3(192),256,0,stream>>>(part, cb5, nullptr, x5, 128,384,8);
    gemmsk_kernel<true ><<<dim3(2,64,4),256,0,stream>>>(x5, cw6, part, 128,4096,384, 96);
    reduce_kernel<false,false><<<dim3(2048),256,0,stream>>>(part, cb6, nullptr, pwe, 128,4096,4);

    // ---- union head ----
    cat8_kernel<<<dim3(128),256,0,stream>>>(pwe, unionf, cat8);
    gemmsk_kernel<false><<<dim3(2,8,32),256,0,stream>>>(cat8, Ww1, part, 128,512,8192, 256);
    reduce_kernel<true ,false><<<dim3(256),256,0,stream>>>(part, bw1, nullptr, hbuf, 128,512,32);
    gemmsk_kernel<false><<<dim3(2,64,4),256,0,stream>>>(hbuf, Ww2, part, 128,4096,512, 128);
    reduce_kernel<true ,false><<<dim3(2048),256,0,stream>>>(part, bw2, nullptr, out + 6528, 128,4096,4);
}